// Round 7
// baseline (564.419 us; speedup 1.0000x reference)
//
#include <hip/hip_runtime.h>
#include <hip/hip_bf16.h>
#include <math.h>

#define F_IN  128
#define HIDC  256
#define NG    8
#define EPS_BN 1e-5f

typedef unsigned short u16;
typedef unsigned int   u32;
typedef __attribute__((ext_vector_type(8))) short bf16x8;
typedef __attribute__((ext_vector_type(4))) float f32x4;
typedef __attribute__((ext_vector_type(2))) float f32x2;

// ---------- bf16 helpers ----------
static __device__ __forceinline__ float b2f(u16 u) {
    return __uint_as_float((u32)u << 16);
}
static __device__ __forceinline__ u16 f2b(float f) {   // RNE
    u32 u = __float_as_uint(f);
    u32 r = (u + 0x7fffu + ((u >> 16) & 1u)) >> 16;
    return (u16)r;
}
static __device__ __forceinline__ u32 pack2(float a, float b) {
    return (u32)f2b(a) | ((u32)f2b(b) << 16);
}
static __device__ __forceinline__ float lk(float v) {   // leaky relu 0.2
    return v >= 0.f ? v : 0.2f * v;
}

// ---------- prep: x->bf16 pairs + 3 weight transposes, one dispatch -------
__global__ void prep_kernel(const float* __restrict__ x,
                            const float* __restrict__ W1,
                            const float* __restrict__ W2,
                            const float* __restrict__ Wq1,
                            u32* __restrict__ xb, u16* __restrict__ WT1,
                            u16* __restrict__ WT2, u16* __restrict__ WQT,
                            int npair) {
    int i = blockIdx.x * 256 + threadIdx.x;
    if (i < npair) {
        float2 v = ((const float2*)x)[i];
        xb[i] = pack2(v.x, v.y);
        return;
    }
    i -= npair;
    if (i < F_IN * HIDC) {
        int nn = i / F_IN, k = i % F_IN;
        WT1[i] = f2b(W1[(long)k * HIDC + nn]);
        return;
    }
    i -= F_IN * HIDC;
    if (i < HIDC * HIDC) {
        int nn = i / HIDC, k = i % HIDC;
        WT2[i] = f2b(W2[(long)k * HIDC + nn]);
        return;
    }
    i -= HIDC * HIDC;
    if (i < HIDC * HIDC) {
        int nn = i / HIDC, k = i % HIDC;
        WQT[i] = f2b(Wq1[(long)k * HIDC + nn]);
    }
}

// ---------- out init: q part = bq2 broadcast, tail = batch as float -------
__global__ void out_init_kernel(float* __restrict__ out,
                                const float* __restrict__ bq2,
                                const int* __restrict__ batch, int N) {
    int i = blockIdx.x * 256 + threadIdx.x;
    if (i < N * 4) out[i] = bq2[i & 3];
    else if (i < N * 5) out[i] = (float)batch[i - N * 4];
}

// ---------- BN coefficients: scale = g*rsqrt(var), bias = beta - mu*scale --
__global__ void bn_coef_kernel(const float* __restrict__ sum,
                               const float* __restrict__ sumsq,
                               const float* __restrict__ gamma,
                               const float* __restrict__ beta,
                               float* __restrict__ scale,
                               float* __restrict__ bias, int N) {
    int c = threadIdx.x;
    float invN = 1.f / (float)N;
    float mu = sum[c] * invN;
    float var = sumsq[c] * invN - mu * mu;
    float inv = rsqrtf(var + EPS_BN);
    float sc = gamma[c] * inv;
    scale[c] = sc;
    bias[c] = beta[c] - mu * sc;
}

// ---------- MFMA GEMM: C[M,256] = act(A)[M,K] @ WT^T, LDS-staged B --------
// MODE 0: plain A, stores C + H=4 alpha logits. MODE 1: BN+relu A, stores C
// + H=1 alpha logits (atomicAdd). MODE 2: BN+relu A, no C store; fused head:
// q[m,j] += relu(acc+gproj+bq1) . Wq2  via quad shfl-reduce + atomicAdd.
template <int K, int MODE>
__global__ __launch_bounds__(256)
void gemm_mfma_kernel(const u16* __restrict__ A, const u16* __restrict__ WT,
                      u16* __restrict__ C, int M,
                      const float* __restrict__ scaleA, const float* __restrict__ biasA,
                      const float* __restrict__ wsrc, const float* __restrict__ wdst,
                      float* __restrict__ asrc, float* __restrict__ adst,
                      const float* __restrict__ gproj, const int* __restrict__ bat,
                      const float* __restrict__ bq1,
                      const float* __restrict__ wq2, float* __restrict__ qout) {
    __shared__ u16 sB[128][K + 8];
    int tid = threadIdx.x;
    int n0 = blockIdx.x * 128;

    constexpr int ROWCH = K * 2 / 16;          // uint4 per row
    const uint4* src = (const uint4*)(WT + (size_t)n0 * K);
    for (int i = tid; i < 128 * ROWCH; i += 256) {
        int r = i / ROWCH, c = i % ROWCH;
        *(uint4*)&sB[r][c * 8] = src[i];
    }
    __syncthreads();

    int wid = tid >> 6, lane = tid & 63;
    int row = lane & 15, quad = lane >> 4;
    int m0 = blockIdx.y * 128 + wid * 32;
    int mf0 = m0, mf1 = m0 + 16;               // M % 16 == 0
    bool v0 = mf0 < M, v1 = mf1 < M;
    if (!v0) return;                            // after barrier: safe
    const u16* Ap0 = A + (size_t)(mf0 + row) * K + quad * 8;
    const u16* Ap1 = A + (size_t)((v1 ? mf1 : mf0) + row) * K + quad * 8;

    f32x4 acc[2][8];
#pragma unroll
    for (int f = 0; f < 2; ++f)
#pragma unroll
        for (int t = 0; t < 8; ++t) acc[f][t] = (f32x4){0.f, 0.f, 0.f, 0.f};

#pragma unroll
    for (int k0 = 0; k0 < K; k0 += 32) {
        bf16x8 a[2];
        a[0] = *(const bf16x8*)(Ap0 + k0);
        a[1] = *(const bf16x8*)(Ap1 + k0);
        if constexpr (MODE != 0) {   // fused BN + relu on A fragments
            int c0 = k0 + quad * 8;
            float4 s0 = *(const float4*)(scaleA + c0);
            float4 s1 = *(const float4*)(scaleA + c0 + 4);
            float4 b0 = *(const float4*)(biasA + c0);
            float4 b1 = *(const float4*)(biasA + c0 + 4);
#pragma unroll
            for (int f = 0; f < 2; ++f) {
                float xv[8];
#pragma unroll
                for (int j = 0; j < 8; ++j) xv[j] = b2f((u16)a[f][j]);
                xv[0] = fmaxf(fmaf(s0.x, xv[0], b0.x), 0.f);
                xv[1] = fmaxf(fmaf(s0.y, xv[1], b0.y), 0.f);
                xv[2] = fmaxf(fmaf(s0.z, xv[2], b0.z), 0.f);
                xv[3] = fmaxf(fmaf(s0.w, xv[3], b0.w), 0.f);
                xv[4] = fmaxf(fmaf(s1.x, xv[4], b1.x), 0.f);
                xv[5] = fmaxf(fmaf(s1.y, xv[5], b1.y), 0.f);
                xv[6] = fmaxf(fmaf(s1.z, xv[6], b1.z), 0.f);
                xv[7] = fmaxf(fmaf(s1.w, xv[7], b1.w), 0.f);
#pragma unroll
                for (int j = 0; j < 8; ++j) a[f][j] = (short)f2b(xv[j]);
            }
        }
#pragma unroll
        for (int t = 0; t < 8; ++t) {
            bf16x8 b = *(const bf16x8*)&sB[t * 16 + row][k0 + quad * 8];
            acc[0][t] = __builtin_amdgcn_mfma_f32_16x16x32_bf16(a[0], b, acc[0][t], 0, 0, 0);
            acc[1][t] = __builtin_amdgcn_mfma_f32_16x16x32_bf16(a[1], b, acc[1][t], 0, 0, 0);
        }
    }

    int mf[2] = {mf0, mf1};
    bool vf[2] = {v0, v1};
    if constexpr (MODE == 2) {       // fused head + q epilogue (no C store)
        float qacc[2][4][4];
#pragma unroll
        for (int f = 0; f < 2; ++f)
#pragma unroll
            for (int r = 0; r < 4; ++r)
#pragma unroll
                for (int j = 0; j < 4; ++j) qacc[f][r][j] = 0.f;
#pragma unroll
        for (int f = 0; f < 2; ++f) {
            if (!vf[f]) continue;
            int bm[4];
#pragma unroll
            for (int r = 0; r < 4; ++r) bm[r] = bat[mf[f] + quad * 4 + r];
#pragma unroll
            for (int t = 0; t < 8; ++t) {
                int n = n0 + t * 16 + row;
                float bq = bq1[n];
                float4 w4 = ((const float4*)wq2)[n];
#pragma unroll
                for (int r = 0; r < 4; ++r) {
                    float v = fmaxf(acc[f][t][r] + gproj[bm[r] * HIDC + n] + bq, 0.f);
                    qacc[f][r][0] = fmaf(v, w4.x, qacc[f][r][0]);
                    qacc[f][r][1] = fmaf(v, w4.y, qacc[f][r][1]);
                    qacc[f][r][2] = fmaf(v, w4.z, qacc[f][r][2]);
                    qacc[f][r][3] = fmaf(v, w4.w, qacc[f][r][3]);
                }
            }
        }
#pragma unroll
        for (int off = 1; off < 16; off <<= 1)
#pragma unroll
            for (int f = 0; f < 2; ++f)
#pragma unroll
                for (int r = 0; r < 4; ++r)
#pragma unroll
                    for (int j = 0; j < 4; ++j)
                        qacc[f][r][j] += __shfl_xor(qacc[f][r][j], off, 64);
        if (row == 0) {
#pragma unroll
            for (int f = 0; f < 2; ++f) {
                if (!vf[f]) continue;
#pragma unroll
                for (int r = 0; r < 4; ++r) {
                    size_t m = mf[f] + quad * 4 + r;
#pragma unroll
                    for (int j = 0; j < 4; ++j)
                        atomicAdd(&qout[m * 4 + j], qacc[f][r][j]);
                }
            }
        }
    } else {
#pragma unroll
        for (int f = 0; f < 2; ++f) {
            if (!vf[f]) continue;
#pragma unroll
            for (int t = 0; t < 8; ++t) {
                int n = n0 + t * 16 + row;
#pragma unroll
                for (int r = 0; r < 4; ++r)
                    C[(size_t)(mf[f] + quad * 4 + r) * HIDC + n] = f2b(acc[f][t][r]);
            }
        }
        if constexpr (MODE == 0) {   // H=4 alpha logits; block owns 2 heads
            float pa[2][2][4] = {}, pd[2][2][4] = {};
#pragma unroll
            for (int t = 0; t < 8; ++t) {
                float ws = wsrc[n0 + t * 16 + row];
                float wd = wdst[n0 + t * 16 + row];
                int hf = t >> 2;
#pragma unroll
                for (int f = 0; f < 2; ++f)
#pragma unroll
                    for (int r = 0; r < 4; ++r) {
                        pa[f][hf][r] = fmaf(acc[f][t][r], ws, pa[f][hf][r]);
                        pd[f][hf][r] = fmaf(acc[f][t][r], wd, pd[f][hf][r]);
                    }
            }
#pragma unroll
            for (int off = 1; off < 16; off <<= 1)
#pragma unroll
                for (int f = 0; f < 2; ++f)
#pragma unroll
                    for (int hf = 0; hf < 2; ++hf)
#pragma unroll
                        for (int r = 0; r < 4; ++r) {
                            pa[f][hf][r] += __shfl_xor(pa[f][hf][r], off, 64);
                            pd[f][hf][r] += __shfl_xor(pd[f][hf][r], off, 64);
                        }
            if (row == 0) {
                int hbase = n0 >> 6;
#pragma unroll
                for (int f = 0; f < 2; ++f) {
                    if (!vf[f]) continue;
#pragma unroll
                    for (int r = 0; r < 4; ++r) {
                        int m = mf[f] + quad * 4 + r;
#pragma unroll
                        for (int hf = 0; hf < 2; ++hf) {
                            asrc[m * 4 + hbase + hf] = pa[f][hf][r];
                            adst[m * 4 + hbase + hf] = pd[f][hf][r];
                        }
                    }
                }
            }
        }
        if constexpr (MODE == 1) {   // H=1 alpha logits; 2 blocks sum via atomics
            float pa[2][4] = {}, pd[2][4] = {};
#pragma unroll
            for (int t = 0; t < 8; ++t) {
                float ws = wsrc[n0 + t * 16 + row];
                float wd = wdst[n0 + t * 16 + row];
#pragma unroll
                for (int f = 0; f < 2; ++f)
#pragma unroll
                    for (int r = 0; r < 4; ++r) {
                        pa[f][r] = fmaf(acc[f][t][r], ws, pa[f][r]);
                        pd[f][r] = fmaf(acc[f][t][r], wd, pd[f][r]);
                    }
            }
#pragma unroll
            for (int off = 1; off < 16; off <<= 1)
#pragma unroll
                for (int f = 0; f < 2; ++f)
#pragma unroll
                    for (int r = 0; r < 4; ++r) {
                        pa[f][r] += __shfl_xor(pa[f][r], off, 64);
                        pd[f][r] += __shfl_xor(pd[f][r], off, 64);
                    }
            if (row == 0) {
#pragma unroll
                for (int f = 0; f < 2; ++f) {
                    if (!vf[f]) continue;
#pragma unroll
                    for (int r = 0; r < 4; ++r) {
                        int m = mf[f] + quad * 4 + r;
                        atomicAdd(&asrc[m], pa[f][r]);
                        atomicAdd(&adst[m], pd[f][r]);
                    }
                }
            }
        }
    }
}

// =================== CSR build (by destination), built once ===============
__global__ void deg_kernel(const int* __restrict__ ei, int E, int N,
                           int* __restrict__ deg) {
    int e = blockIdx.x * blockDim.x + threadIdx.x;
    if (e >= E + N) return;
    int d = (e < E) ? ei[E + e] : (e - E);
    atomicAdd(&deg[d], 1);
}

__global__ __launch_bounds__(256)
void scan_phase1(const int* __restrict__ deg, int* __restrict__ part,
                 int* __restrict__ bsum, int N) {
    __shared__ int tmp[256];
    int i = blockIdx.x * 256 + threadIdx.x;
    int v = (i < N) ? deg[i] : 0;
    tmp[threadIdx.x] = v;
    __syncthreads();
    for (int off = 1; off < 256; off <<= 1) {
        int t = (threadIdx.x >= off) ? tmp[threadIdx.x - off] : 0;
        __syncthreads();
        tmp[threadIdx.x] += t;
        __syncthreads();
    }
    if (i < N) part[i] = tmp[threadIdx.x];
    if (threadIdx.x == 255) bsum[blockIdx.x] = tmp[255];
}
__global__ __launch_bounds__(256)
void scan_phase2(int* __restrict__ bsum, int nb) {
    __shared__ int tmp[256];
    int v = (threadIdx.x < nb) ? bsum[threadIdx.x] : 0;
    tmp[threadIdx.x] = v;
    __syncthreads();
    for (int off = 1; off < 256; off <<= 1) {
        int t = (threadIdx.x >= off) ? tmp[threadIdx.x - off] : 0;
        __syncthreads();
        tmp[threadIdx.x] += t;
        __syncthreads();
    }
    if (threadIdx.x < nb)
        bsum[threadIdx.x] = threadIdx.x ? tmp[threadIdx.x - 1] : 0;
}
__global__ __launch_bounds__(256)
void scan_phase3(const int* __restrict__ part, const int* __restrict__ bsum,
                 int* __restrict__ rowptr, int N) {
    int i = blockIdx.x * 256 + threadIdx.x;
    if (i < N) rowptr[i + 1] = part[i] + bsum[blockIdx.x];
    if (i == 0) rowptr[0] = 0;
}

__global__ void fill_kernel(const int* __restrict__ ei, int E, int N,
                            const int* __restrict__ rowptr,
                            int* __restrict__ cur, int* __restrict__ csr_src) {
    int e = blockIdx.x * blockDim.x + threadIdx.x;
    if (e >= E + N) return;
    int s = (e < E) ? ei[e] : (e - E);
    int d = (e < E) ? ei[E + e] : (e - E);
    int pos = rowptr[d] + atomicAdd(&cur[d], 1);
    csr_src[pos] = s;
}

// ========== fused GAT edge-softmax + aggregation (online softmax) =========
// wave per dst node. LDS stages (row byte-offset, alpha) uint2 per edge
// (per head); inner loop: 1 ds_read_b64 + 1 v_add + 1 global dwordx2 +
// packed-f32 fma accumulate.
template <int H>
__global__ __launch_bounds__(256)
void gat_gather_kernel(const int* __restrict__ rowptr,
                       const int* __restrict__ csr_src,
                       const float* __restrict__ asrc,
                       const float* __restrict__ adst,
                       const u16* __restrict__ h,
                       u16* __restrict__ agg, int N) {
    __shared__ __align__(16) uint2 s_ed[4][64 * H];
    int wid = threadIdx.x >> 6, lane = threadIdx.x & 63;
    int n = blockIdx.x * 4 + wid;
    if (n >= N) return;
    int start = rowptr[n], end = rowptr[n + 1];
    float ad[H];
#pragma unroll
    for (int hh = 0; hh < H; ++hh) ad[hh] = adst[n * H + hh];

    // pass 1: online softmax stats (m, d) per head
    float m[H], d[H];
#pragma unroll
    for (int hh = 0; hh < H; ++hh) { m[hh] = -1e30f; d[hh] = 0.f; }
    for (int i = start + lane; i < end; i += 64) {
        int s = csr_src[i];
        float av[H];
        if (H == 4) {
            float4 a4 = *(const float4*)(asrc + s * 4);
            av[0] = a4.x; av[1 % H] = a4.y; av[2 % H] = a4.z; av[3 % H] = a4.w;
        } else {
            av[0] = asrc[s];
        }
#pragma unroll
        for (int hh = 0; hh < H; ++hh) {
            float v = lk(av[hh] + ad[hh]);
            float mn = fmaxf(m[hh], v);
            d[hh] = fmaf(d[hh], __expf(m[hh] - mn), __expf(v - mn));
            m[hh] = mn;
        }
    }
#pragma unroll
    for (int off = 1; off < 64; off <<= 1)
#pragma unroll
        for (int hh = 0; hh < H; ++hh) {
            float mo = __shfl_xor(m[hh], off, 64);
            float dd = __shfl_xor(d[hh], off, 64);
            float mn = fmaxf(m[hh], mo);
            d[hh] = d[hh] * __expf(m[hh] - mn) + dd * __expf(mo - mn);
            m[hh] = mn;
        }
    float invd[H];
#pragma unroll
    for (int hh = 0; hh < H; ++hh) invd[hh] = 1.f / (d[hh] + 1e-16f);

    // pass 2: accumulate; lane owns channels [lane*4, lane*4+4)
    f32x2 acc01 = {0.f, 0.f}, acc23 = {0.f, 0.f};
    const int head = (H == 4) ? (lane >> 4) : 0;
    const char* hb = (const char*)h;
    const u32 laneB = (u32)lane * 8u;
    for (int base = start; base < end; base += 64) {
        int cnt = min(64, end - base);
        if (lane < cnt) {
            int s = csr_src[base + lane];
            u32 off = (u32)s * (u32)(HIDC * 2);     // row byte offset
            if (H == 4) {
                float4 a4 = *(const float4*)(asrc + s * 4);
                uint4 w0, w1;
                w0.x = off;
                w0.y = __float_as_uint(__expf(lk(a4.x + ad[0]) - m[0]) * invd[0]);
                w0.z = off;
                w0.w = __float_as_uint(__expf(lk(a4.y + ad[1 % H]) - m[1 % H]) * invd[1 % H]);
                w1.x = off;
                w1.y = __float_as_uint(__expf(lk(a4.z + ad[2 % H]) - m[2 % H]) * invd[2 % H]);
                w1.z = off;
                w1.w = __float_as_uint(__expf(lk(a4.w + ad[3 % H]) - m[3 % H]) * invd[3 % H]);
                *(uint4*)&s_ed[wid][lane * 4] = w0;
                *(uint4*)&s_ed[wid][lane * 4 + 2] = w1;
            } else {
                float al = __expf(lk(asrc[s] + ad[0]) - m[0]) * invd[0];
                s_ed[wid][lane] = make_uint2(off, __float_as_uint(al));
            }
        }
        // wave-synchronous LDS: DS ops from one wave complete in order
#define GBODY(J) {                                                             \
            uint2 e_ = s_ed[wid][(H == 4) ? ((J) * 4 + head) : (J)];           \
            const uint2 hv_ = *(const uint2*)(hb + (size_t)(e_.x + laneB));    \
            float al_ = __uint_as_float(e_.y);                                 \
            f32x2 al2_ = {al_, al_};                                           \
            f32x2 v01_ = { __uint_as_float(hv_.x << 16),                       \
                           __uint_as_float(hv_.x & 0xffff0000u) };             \
            f32x2 v23_ = { __uint_as_float(hv_.y << 16),                       \
                           __uint_as_float(hv_.y & 0xffff0000u) };             \
            acc01 = __builtin_elementwise_fma(v01_, al2_, acc01);              \
            acc23 = __builtin_elementwise_fma(v23_, al2_, acc23); }
        int j = 0;
        for (; j + 4 <= cnt; j += 4) { GBODY(j) GBODY(j + 1) GBODY(j + 2) GBODY(j + 3) }
        for (; j < cnt; ++j) GBODY(j)
#undef GBODY
    }
    uint2 o;
    o.x = pack2(acc01.x, acc01.y);
    o.y = pack2(acc23.x, acc23.y);
    ((uint2*)(agg + (size_t)n * HIDC))[lane] = o;
}

// ---------- BatchNorm stats (bf16 in, fp32 accumulate) ----------
__global__ __launch_bounds__(256)
void bn_stats_kernel(const u16* __restrict__ h, int N,
                     float* __restrict__ sum, float* __restrict__ sumsq) {
    int c = threadIdx.x;
    int r0 = blockIdx.x * 128;
    int rend = min(r0 + 128, N);
    float s = 0.f, q = 0.f;
    for (int r = r0; r < rend; ++r) {
        float v = b2f(h[(long)r * HIDC + c]);
        s += v;
        q += v * v;
    }
    atomicAdd(&sum[c], s);
    atomicAdd(&sumsq[c], q);
}

// ---------- graph mean pooling with inline BN+relu (batch sorted) ---------
__global__ __launch_bounds__(256)
void pool_bn_kernel(const u16* __restrict__ h, const int* __restrict__ batch,
                    int N, const float* __restrict__ scale,
                    const float* __restrict__ bias,
                    float* __restrict__ gsum, float* __restrict__ gcnt) {
    int c = threadIdx.x;
    float sc = scale[c], bi = bias[c];
    int r0 = blockIdx.x * 128;
    int rend = min(r0 + 128, N);
    int curb = -1;
    float acc = 0.f;
    for (int r = r0; r < rend; ++r) {
        int b = batch[r];
        if (b != curb) {
            if (curb >= 0) atomicAdd(&gsum[curb * HIDC + c], acc);
            curb = b; acc = 0.f;
        }
        acc += fmaxf(fmaf(sc, b2f(h[(long)r * HIDC + c]), bi), 0.f);
    }
    if (curb >= 0) atomicAdd(&gsum[curb * HIDC + c], acc);
    if (c == 0) {
        int prev = -1; float cnt = 0.f;
        for (int r = r0; r < rend; ++r) {
            int b = batch[r];
            if (b != prev) {
                if (prev >= 0) atomicAdd(&gcnt[prev], cnt);
                prev = b; cnt = 0.f;
            }
            cnt += 1.f;
        }
        if (prev >= 0) atomicAdd(&gcnt[prev], cnt);
    }
}

// ---------- gmean + projection: gproj[b,c] = Σ_k gmean[b,k]*Wq1[256+k,c] --
__global__ __launch_bounds__(256)
void gmean_gproj_kernel(const float* __restrict__ gsum,
                        const float* __restrict__ gcnt,
                        const float* __restrict__ Wq1,
                        float* __restrict__ gproj) {
    int b = blockIdx.x, c = threadIdx.x;
    __shared__ float gm[HIDC];
    gm[c] = gsum[b * HIDC + c] / fmaxf(gcnt[b], 1.f);
    __syncthreads();
    float acc = 0.f;
    for (int k = 0; k < HIDC; ++k)
        acc = fmaf(gm[k], Wq1[(long)(HIDC + k) * HIDC + c], acc);
    gproj[b * HIDC + c] = acc;
}

extern "C" void kernel_launch(void* const* d_in, const int* in_sizes, int n_in,
                              void* d_out, int out_size, void* d_ws, size_t ws_size,
                              hipStream_t stream) {
    const float* x   = (const float*)d_in[0];
    const int*   ei  = (const int*)d_in[1];
    const int*   bat = (const int*)d_in[2];
    const float* W1  = (const float*)d_in[3];
    const float* as1 = (const float*)d_in[4];
    const float* ad1 = (const float*)d_in[5];
    const float* g1  = (const float*)d_in[7];
    const float* be1 = (const float*)d_in[8];
    const float* W2  = (const float*)d_in[9];
    const float* as2 = (const float*)d_in[10];
    const float* ad2 = (const float*)d_in[11];
    const float* g2  = (const float*)d_in[13];
    const float* be2 = (const float*)d_in[14];
    const float* Wq1 = (const float*)d_in[15];
    const float* bq1 = (const float*)d_in[16];
    const float* Wq2 = (const float*)d_in[17];
    const float* bq2 = (const float*)d_in[18];
    float* out = (float*)d_out;

    const int N = in_sizes[0] / F_IN;   // 50000
    const int E = in_sizes[1] / 2;      // 800000
    const int Etot = E + N;
    const int nb = (N + 255) / 256;

    const size_t hbytes = (size_t)N * HIDC * sizeof(u16);   // 25.6 MB
    char* p = (char*)d_ws;
    auto alloc = [&](size_t sz) { char* q = p; p += (sz + 255) & ~(size_t)255; return q; };
    u16* BX   = (u16*)alloc((size_t)N * F_IN * sizeof(u16)); // bf16 x
    u16* BH   = (u16*)alloc(hbytes);   // h1 -> h2
    u16* BA   = (u16*)alloc(hbytes);   // agg1 -> agg2
    u16* WT1  = (u16*)alloc((size_t)HIDC * F_IN * sizeof(u16));
    u16* WT2  = (u16*)alloc((size_t)HIDC * HIDC * sizeof(u16));
    u16* WQT  = (u16*)alloc((size_t)HIDC * HIDC * sizeof(u16));
    // pairs sharing one memset are single allocations (alloc rounds to 256B!)
    float* asrc = (float*)alloc((size_t)N * 4 * 4 * 2);      // asrc | adst
    float* adst = asrc + (size_t)N * 4;
    int* rowptr  = (int*)alloc((size_t)(N + 1) * 4);
    int* csr_src = (int*)alloc((size_t)Etot * 4);
    int* cur     = (int*)alloc((size_t)N * 4 * 2);           // deg | fill cursor
    int* cur2    = cur + N;
    int* part    = (int*)alloc((size_t)N * 4);
    int* bsum    = (int*)alloc((size_t)nb * 4);
    float* bnsum = (float*)alloc(HIDC * 4 * 2);              // bnsum | bnsq
    float* bnsq  = bnsum + HIDC;
    float* sc1   = (float*)alloc(HIDC * 4);
    float* bi1   = (float*)alloc(HIDC * 4);
    float* sc2   = (float*)alloc(HIDC * 4);
    float* bi2   = (float*)alloc(HIDC * 4);
    float* gsum  = (float*)alloc((NG * HIDC + NG) * 4);      // gsum | gcnt
    float* gcnt  = gsum + NG * HIDC;
    float* gproj = (float*)alloc(NG * HIDC * 4);

    dim3 gemmGrid(2, (N + 127) / 128);   // block = 128 rows x 128 cols
    int edgeBlocks = (Etot + 255) / 256;
    int nodeBlocksW = (N + 3) / 4;
    int npair = N * F_IN / 2;
    int prepTotal = npair + F_IN * HIDC + 2 * HIDC * HIDC;

    // ===================== CSR build (once) ==============================
    hipMemsetAsync(cur, 0, (size_t)N * 4 * 2, stream);        // cur + cur2
    deg_kernel<<<edgeBlocks, 256, 0, stream>>>(ei, E, N, cur);
    scan_phase1<<<nb, 256, 0, stream>>>(cur, part, bsum, N);
    scan_phase2<<<1, 256, 0, stream>>>(bsum, nb);
    scan_phase3<<<nb, 256, 0, stream>>>(part, bsum, rowptr, N);
    fill_kernel<<<edgeBlocks, 256, 0, stream>>>(ei, E, N, rowptr, cur2, csr_src);

    // ===================== prep (1 dispatch) =============================
    prep_kernel<<<(prepTotal + 255) / 256, 256, 0, stream>>>(
        x, W1, W2, Wq1, (u32*)BX, WT1, WT2, WQT, npair);

    // ===================== Layer 1: GEMM(+alpha4) -> gather -> BN stats ==
    gemm_mfma_kernel<F_IN, 0><<<gemmGrid, 256, 0, stream>>>(
        BX, WT1, BH, N, nullptr, nullptr, as1, ad1, asrc, adst,
        nullptr, nullptr, nullptr, nullptr, nullptr);
    gat_gather_kernel<4><<<nodeBlocksW, 256, 0, stream>>>(rowptr, csr_src, asrc, adst, BH, BA, N);
    hipMemsetAsync(bnsum, 0, HIDC * 4 * 2, stream);           // bnsum + bnsq
    bn_stats_kernel<<<(N + 127) / 128, 256, 0, stream>>>(BA, N, bnsum, bnsq);
    bn_coef_kernel<<<1, HIDC, 0, stream>>>(bnsum, bnsq, g1, be1, sc1, bi1, N);

    // ===================== Layer 2: GEMM(BN-A, +alpha1) -> gather -> BN ==
    hipMemsetAsync(asrc, 0, (size_t)N * 4 * 4 * 2, stream);   // asrc + adst
    gemm_mfma_kernel<HIDC, 1><<<gemmGrid, 256, 0, stream>>>(
        BA, WT2, BH, N, sc1, bi1, as2, ad2, asrc, adst,
        nullptr, nullptr, nullptr, nullptr, nullptr);
    gat_gather_kernel<1><<<nodeBlocksW, 256, 0, stream>>>(rowptr, csr_src, asrc, adst, BH, BA, N);
    hipMemsetAsync(bnsum, 0, HIDC * 4 * 2, stream);
    bn_stats_kernel<<<(N + 127) / 128, 256, 0, stream>>>(BA, N, bnsum, bnsq);
    bn_coef_kernel<<<1, HIDC, 0, stream>>>(bnsum, bnsq, g2, be2, sc2, bi2, N);

    // ===================== Pool (BN inline) + projection + out init ======
    hipMemsetAsync(gsum, 0, (NG * HIDC + NG) * 4, stream);    // gsum + gcnt
    pool_bn_kernel<<<(N + 127) / 128, 256, 0, stream>>>(BA, bat, N, sc2, bi2, gsum, gcnt);
    gmean_gproj_kernel<<<NG, HIDC, 0, stream>>>(gsum, gcnt, Wq1, gproj);
    out_init_kernel<<<(N * 5 + 255) / 256, 256, 0, stream>>>(out, bq2, bat, N);

    // ===================== Head: GEMM(BN-A, fused q epilogue) ============
    gemm_mfma_kernel<HIDC, 2><<<gemmGrid, 256, 0, stream>>>(
        BA, WQT, nullptr, N, sc2, bi2, nullptr, nullptr, nullptr, nullptr,
        gproj, bat, bq1, Wq2, out);
}

// Round 8
// 545.683 us; speedup vs baseline: 1.0343x; 1.0343x over previous
//
#include <hip/hip_runtime.h>
#include <hip/hip_bf16.h>
#include <math.h>

#define F_IN  128
#define HIDC  256
#define NG    8
#define EPS_BN 1e-5f

typedef unsigned short u16;
typedef unsigned int   u32;
typedef unsigned char  u8;
typedef __attribute__((ext_vector_type(8))) short bf16x8;
typedef __attribute__((ext_vector_type(4))) float f32x4;
typedef __attribute__((ext_vector_type(2))) float f32x2;

// ---------- bf16 helpers ----------
static __device__ __forceinline__ float b2f(u16 u) {
    return __uint_as_float((u32)u << 16);
}
static __device__ __forceinline__ u16 f2b(float f) {   // RNE
    u32 u = __float_as_uint(f);
    u32 r = (u + 0x7fffu + ((u >> 16) & 1u)) >> 16;
    return (u16)r;
}
static __device__ __forceinline__ u32 pack2(float a, float b) {
    return (u32)f2b(a) | ((u32)f2b(b) << 16);
}
static __device__ __forceinline__ float lk(float v) {   // leaky relu 0.2
    return v >= 0.f ? v : 0.2f * v;
}
static __device__ __forceinline__ u8 f2fp8(float v) {  // e4m3 via HW cvt
    return (u8)__builtin_amdgcn_cvt_pk_fp8_f32(v, v, 0, false);
}

// ---------- prep: x->bf16 pairs + 3 weight transposes, one dispatch -------
__global__ void prep_kernel(const float* __restrict__ x,
                            const float* __restrict__ W1,
                            const float* __restrict__ W2,
                            const float* __restrict__ Wq1,
                            u32* __restrict__ xb, u16* __restrict__ WT1,
                            u16* __restrict__ WT2, u16* __restrict__ WQT,
                            int npair) {
    int i = blockIdx.x * 256 + threadIdx.x;
    if (i < npair) {
        float2 v = ((const float2*)x)[i];
        xb[i] = pack2(v.x, v.y);
        return;
    }
    i -= npair;
    if (i < F_IN * HIDC) {
        int nn = i / F_IN, k = i % F_IN;
        WT1[i] = f2b(W1[(long)k * HIDC + nn]);
        return;
    }
    i -= F_IN * HIDC;
    if (i < HIDC * HIDC) {
        int nn = i / HIDC, k = i % HIDC;
        WT2[i] = f2b(W2[(long)k * HIDC + nn]);
        return;
    }
    i -= HIDC * HIDC;
    if (i < HIDC * HIDC) {
        int nn = i / HIDC, k = i % HIDC;
        WQT[i] = f2b(Wq1[(long)k * HIDC + nn]);
    }
}

// ---------- out init: q part = bq2 broadcast, tail = batch as float -------
__global__ void out_init_kernel(float* __restrict__ out,
                                const float* __restrict__ bq2,
                                const int* __restrict__ batch, int N) {
    int i = blockIdx.x * 256 + threadIdx.x;
    if (i < N * 4) out[i] = bq2[i & 3];
    else if (i < N * 5) out[i] = (float)batch[i - N * 4];
}

// ---------- BN coefficients: scale = g*rsqrt(var), bias = beta - mu*scale --
__global__ void bn_coef_kernel(const float* __restrict__ sum,
                               const float* __restrict__ sumsq,
                               const float* __restrict__ gamma,
                               const float* __restrict__ beta,
                               float* __restrict__ scale,
                               float* __restrict__ bias, int N) {
    int c = threadIdx.x;
    float invN = 1.f / (float)N;
    float mu = sum[c] * invN;
    float var = sumsq[c] * invN - mu * mu;
    float inv = rsqrtf(var + EPS_BN);
    float sc = gamma[c] * inv;
    scale[c] = sc;
    bias[c] = beta[c] - mu * sc;
}

// ---------- MFMA GEMM: C = act(A)[M,K] @ WT^T, LDS-staged B ---------------
// MODE 0: plain A, stores C (fp8 e4m3) + H=4 alpha logits (fp32).
// MODE 1: BN+relu A, stores C (fp8) + H=1 alpha logits (atomicAdd).
// MODE 2: BN+relu A, no C store; fused head: q += relu(acc+gproj+bq1).Wq2.
// Alpha logits always from fp32 accumulators (never quantized).
template <int K, int MODE>
__global__ __launch_bounds__(256)
void gemm_mfma_kernel(const u16* __restrict__ A, const u16* __restrict__ WT,
                      u8* __restrict__ C, int M,
                      const float* __restrict__ scaleA, const float* __restrict__ biasA,
                      const float* __restrict__ wsrc, const float* __restrict__ wdst,
                      float* __restrict__ asrc, float* __restrict__ adst,
                      const float* __restrict__ gproj, const int* __restrict__ bat,
                      const float* __restrict__ bq1,
                      const float* __restrict__ wq2, float* __restrict__ qout) {
    __shared__ u16 sB[128][K + 8];
    int tid = threadIdx.x;
    int n0 = blockIdx.x * 128;

    constexpr int ROWCH = K * 2 / 16;          // uint4 per row
    const uint4* src = (const uint4*)(WT + (size_t)n0 * K);
    for (int i = tid; i < 128 * ROWCH; i += 256) {
        int r = i / ROWCH, c = i % ROWCH;
        *(uint4*)&sB[r][c * 8] = src[i];
    }
    __syncthreads();

    int wid = tid >> 6, lane = tid & 63;
    int row = lane & 15, quad = lane >> 4;
    int m0 = blockIdx.y * 128 + wid * 32;
    int mf0 = m0, mf1 = m0 + 16;               // M % 16 == 0
    bool v0 = mf0 < M, v1 = mf1 < M;
    if (!v0) return;                            // after barrier: safe
    const u16* Ap0 = A + (size_t)(mf0 + row) * K + quad * 8;
    const u16* Ap1 = A + (size_t)((v1 ? mf1 : mf0) + row) * K + quad * 8;

    f32x4 acc[2][8];
#pragma unroll
    for (int f = 0; f < 2; ++f)
#pragma unroll
        for (int t = 0; t < 8; ++t) acc[f][t] = (f32x4){0.f, 0.f, 0.f, 0.f};

#pragma unroll
    for (int k0 = 0; k0 < K; k0 += 32) {
        bf16x8 a[2];
        a[0] = *(const bf16x8*)(Ap0 + k0);
        a[1] = *(const bf16x8*)(Ap1 + k0);
        if constexpr (MODE != 0) {   // fused BN + relu on A fragments
            int c0 = k0 + quad * 8;
            float4 s0 = *(const float4*)(scaleA + c0);
            float4 s1 = *(const float4*)(scaleA + c0 + 4);
            float4 b0 = *(const float4*)(biasA + c0);
            float4 b1 = *(const float4*)(biasA + c0 + 4);
#pragma unroll
            for (int f = 0; f < 2; ++f) {
                float xv[8];
#pragma unroll
                for (int j = 0; j < 8; ++j) xv[j] = b2f((u16)a[f][j]);
                xv[0] = fmaxf(fmaf(s0.x, xv[0], b0.x), 0.f);
                xv[1] = fmaxf(fmaf(s0.y, xv[1], b0.y), 0.f);
                xv[2] = fmaxf(fmaf(s0.z, xv[2], b0.z), 0.f);
                xv[3] = fmaxf(fmaf(s0.w, xv[3], b0.w), 0.f);
                xv[4] = fmaxf(fmaf(s1.x, xv[4], b1.x), 0.f);
                xv[5] = fmaxf(fmaf(s1.y, xv[5], b1.y), 0.f);
                xv[6] = fmaxf(fmaf(s1.z, xv[6], b1.z), 0.f);
                xv[7] = fmaxf(fmaf(s1.w, xv[7], b1.w), 0.f);
#pragma unroll
                for (int j = 0; j < 8; ++j) a[f][j] = (short)f2b(xv[j]);
            }
        }
#pragma unroll
        for (int t = 0; t < 8; ++t) {
            bf16x8 b = *(const bf16x8*)&sB[t * 16 + row][k0 + quad * 8];
            acc[0][t] = __builtin_amdgcn_mfma_f32_16x16x32_bf16(a[0], b, acc[0][t], 0, 0, 0);
            acc[1][t] = __builtin_amdgcn_mfma_f32_16x16x32_bf16(a[1], b, acc[1][t], 0, 0, 0);
        }
    }

    int mf[2] = {mf0, mf1};
    bool vf[2] = {v0, v1};
    if constexpr (MODE == 2) {       // fused head + q epilogue (no C store)
        float qacc[2][4][4];
#pragma unroll
        for (int f = 0; f < 2; ++f)
#pragma unroll
            for (int r = 0; r < 4; ++r)
#pragma unroll
                for (int j = 0; j < 4; ++j) qacc[f][r][j] = 0.f;
#pragma unroll
        for (int f = 0; f < 2; ++f) {
            if (!vf[f]) continue;
            int bm[4];
#pragma unroll
            for (int r = 0; r < 4; ++r) bm[r] = bat[mf[f] + quad * 4 + r];
#pragma unroll
            for (int t = 0; t < 8; ++t) {
                int n = n0 + t * 16 + row;
                float bq = bq1[n];
                float4 w4 = ((const float4*)wq2)[n];
#pragma unroll
                for (int r = 0; r < 4; ++r) {
                    float v = fmaxf(acc[f][t][r] + gproj[bm[r] * HIDC + n] + bq, 0.f);
                    qacc[f][r][0] = fmaf(v, w4.x, qacc[f][r][0]);
                    qacc[f][r][1] = fmaf(v, w4.y, qacc[f][r][1]);
                    qacc[f][r][2] = fmaf(v, w4.z, qacc[f][r][2]);
                    qacc[f][r][3] = fmaf(v, w4.w, qacc[f][r][3]);
                }
            }
        }
#pragma unroll
        for (int off = 1; off < 16; off <<= 1)
#pragma unroll
            for (int f = 0; f < 2; ++f)
#pragma unroll
                for (int r = 0; r < 4; ++r)
#pragma unroll
                    for (int j = 0; j < 4; ++j)
                        qacc[f][r][j] += __shfl_xor(qacc[f][r][j], off, 64);
        if (row == 0) {
#pragma unroll
            for (int f = 0; f < 2; ++f) {
                if (!vf[f]) continue;
#pragma unroll
                for (int r = 0; r < 4; ++r) {
                    size_t m = mf[f] + quad * 4 + r;
#pragma unroll
                    for (int j = 0; j < 4; ++j)
                        atomicAdd(&qout[m * 4 + j], qacc[f][r][j]);
                }
            }
        }
    } else {
#pragma unroll
        for (int f = 0; f < 2; ++f) {
            if (!vf[f]) continue;
#pragma unroll
            for (int t = 0; t < 8; ++t) {
                int n = n0 + t * 16 + row;
#pragma unroll
                for (int r = 0; r < 4; ++r)
                    C[(size_t)(mf[f] + quad * 4 + r) * HIDC + n] = f2fp8(acc[f][t][r]);
            }
        }
        if constexpr (MODE == 0) {   // H=4 alpha logits; block owns 2 heads
            float pa[2][2][4] = {}, pd[2][2][4] = {};
#pragma unroll
            for (int t = 0; t < 8; ++t) {
                float ws = wsrc[n0 + t * 16 + row];
                float wd = wdst[n0 + t * 16 + row];
                int hf = t >> 2;
#pragma unroll
                for (int f = 0; f < 2; ++f)
#pragma unroll
                    for (int r = 0; r < 4; ++r) {
                        pa[f][hf][r] = fmaf(acc[f][t][r], ws, pa[f][hf][r]);
                        pd[f][hf][r] = fmaf(acc[f][t][r], wd, pd[f][hf][r]);
                    }
            }
#pragma unroll
            for (int off = 1; off < 16; off <<= 1)
#pragma unroll
                for (int f = 0; f < 2; ++f)
#pragma unroll
                    for (int hf = 0; hf < 2; ++hf)
#pragma unroll
                        for (int r = 0; r < 4; ++r) {
                            pa[f][hf][r] += __shfl_xor(pa[f][hf][r], off, 64);
                            pd[f][hf][r] += __shfl_xor(pd[f][hf][r], off, 64);
                        }
            if (row == 0) {
                int hbase = n0 >> 6;
#pragma unroll
                for (int f = 0; f < 2; ++f) {
                    if (!vf[f]) continue;
#pragma unroll
                    for (int r = 0; r < 4; ++r) {
                        int m = mf[f] + quad * 4 + r;
#pragma unroll
                        for (int hf = 0; hf < 2; ++hf) {
                            asrc[m * 4 + hbase + hf] = pa[f][hf][r];
                            adst[m * 4 + hbase + hf] = pd[f][hf][r];
                        }
                    }
                }
            }
        }
        if constexpr (MODE == 1) {   // H=1 alpha logits; 2 blocks sum via atomics
            float pa[2][4] = {}, pd[2][4] = {};
#pragma unroll
            for (int t = 0; t < 8; ++t) {
                float ws = wsrc[n0 + t * 16 + row];
                float wd = wdst[n0 + t * 16 + row];
#pragma unroll
                for (int f = 0; f < 2; ++f)
#pragma unroll
                    for (int r = 0; r < 4; ++r) {
                        pa[f][r] = fmaf(acc[f][t][r], ws, pa[f][r]);
                        pd[f][r] = fmaf(acc[f][t][r], wd, pd[f][r]);
                    }
            }
#pragma unroll
            for (int off = 1; off < 16; off <<= 1)
#pragma unroll
                for (int f = 0; f < 2; ++f)
#pragma unroll
                    for (int r = 0; r < 4; ++r) {
                        pa[f][r] += __shfl_xor(pa[f][r], off, 64);
                        pd[f][r] += __shfl_xor(pd[f][r], off, 64);
                    }
            if (row == 0) {
#pragma unroll
                for (int f = 0; f < 2; ++f) {
                    if (!vf[f]) continue;
#pragma unroll
                    for (int r = 0; r < 4; ++r) {
                        int m = mf[f] + quad * 4 + r;
                        atomicAdd(&asrc[m], pa[f][r]);
                        atomicAdd(&adst[m], pd[f][r]);
                    }
                }
            }
        }
    }
}

// =================== CSR build (by destination), built once ===============
__global__ void deg_kernel(const int* __restrict__ ei, int E, int N,
                           int* __restrict__ deg) {
    int e = blockIdx.x * blockDim.x + threadIdx.x;
    if (e >= E + N) return;
    int d = (e < E) ? ei[E + e] : (e - E);
    atomicAdd(&deg[d], 1);
}

__global__ __launch_bounds__(256)
void scan_phase1(const int* __restrict__ deg, int* __restrict__ part,
                 int* __restrict__ bsum, int N) {
    __shared__ int tmp[256];
    int i = blockIdx.x * 256 + threadIdx.x;
    int v = (i < N) ? deg[i] : 0;
    tmp[threadIdx.x] = v;
    __syncthreads();
    for (int off = 1; off < 256; off <<= 1) {
        int t = (threadIdx.x >= off) ? tmp[threadIdx.x - off] : 0;
        __syncthreads();
        tmp[threadIdx.x] += t;
        __syncthreads();
    }
    if (i < N) part[i] = tmp[threadIdx.x];
    if (threadIdx.x == 255) bsum[blockIdx.x] = tmp[255];
}
__global__ __launch_bounds__(256)
void scan_phase2(int* __restrict__ bsum, int nb) {
    __shared__ int tmp[256];
    int v = (threadIdx.x < nb) ? bsum[threadIdx.x] : 0;
    tmp[threadIdx.x] = v;
    __syncthreads();
    for (int off = 1; off < 256; off <<= 1) {
        int t = (threadIdx.x >= off) ? tmp[threadIdx.x - off] : 0;
        __syncthreads();
        tmp[threadIdx.x] += t;
        __syncthreads();
    }
    if (threadIdx.x < nb)
        bsum[threadIdx.x] = threadIdx.x ? tmp[threadIdx.x - 1] : 0;
}
__global__ __launch_bounds__(256)
void scan_phase3(const int* __restrict__ part, const int* __restrict__ bsum,
                 int* __restrict__ rowptr, int N) {
    int i = blockIdx.x * 256 + threadIdx.x;
    if (i < N) rowptr[i + 1] = part[i] + bsum[blockIdx.x];
    if (i == 0) rowptr[0] = 0;
}

__global__ void fill_kernel(const int* __restrict__ ei, int E, int N,
                            const int* __restrict__ rowptr,
                            int* __restrict__ cur, int* __restrict__ csr_src) {
    int e = blockIdx.x * blockDim.x + threadIdx.x;
    if (e >= E + N) return;
    int s = (e < E) ? ei[e] : (e - E);
    int d = (e < E) ? ei[E + e] : (e - E);
    int pos = rowptr[d] + atomicAdd(&cur[d], 1);
    csr_src[pos] = s;
}

// ========== fused GAT edge-softmax + aggregation (online softmax) =========
// wave per dst node. h rows are fp8 e4m3 (256 B/row): per edge, 1 ds_read_b64
// (offset, alpha), 1 global dword (4 ch), 2 HW fp8->f32 cvt, 2 packed fma.
// Alpha logits (asrc/adst) remain fp32; agg output remains bf16.
template <int H>
__global__ __launch_bounds__(256)
void gat_gather_kernel(const int* __restrict__ rowptr,
                       const int* __restrict__ csr_src,
                       const float* __restrict__ asrc,
                       const float* __restrict__ adst,
                       const u8* __restrict__ h,
                       u16* __restrict__ agg, int N) {
    __shared__ __align__(16) uint2 s_ed[4][64 * H];
    int wid = threadIdx.x >> 6, lane = threadIdx.x & 63;
    int n = blockIdx.x * 4 + wid;
    if (n >= N) return;
    int start = rowptr[n], end = rowptr[n + 1];
    float ad[H];
#pragma unroll
    for (int hh = 0; hh < H; ++hh) ad[hh] = adst[n * H + hh];

    // pass 1: online softmax stats (m, d) per head
    float m[H], d[H];
#pragma unroll
    for (int hh = 0; hh < H; ++hh) { m[hh] = -1e30f; d[hh] = 0.f; }
    for (int i = start + lane; i < end; i += 64) {
        int s = csr_src[i];
        float av[H];
        if (H == 4) {
            float4 a4 = *(const float4*)(asrc + s * 4);
            av[0] = a4.x; av[1 % H] = a4.y; av[2 % H] = a4.z; av[3 % H] = a4.w;
        } else {
            av[0] = asrc[s];
        }
#pragma unroll
        for (int hh = 0; hh < H; ++hh) {
            float v = lk(av[hh] + ad[hh]);
            float mn = fmaxf(m[hh], v);
            d[hh] = fmaf(d[hh], __expf(m[hh] - mn), __expf(v - mn));
            m[hh] = mn;
        }
    }
#pragma unroll
    for (int off = 1; off < 64; off <<= 1)
#pragma unroll
        for (int hh = 0; hh < H; ++hh) {
            float mo = __shfl_xor(m[hh], off, 64);
            float dd = __shfl_xor(d[hh], off, 64);
            float mn = fmaxf(m[hh], mo);
            d[hh] = d[hh] * __expf(m[hh] - mn) + dd * __expf(mo - mn);
            m[hh] = mn;
        }
    float invd[H];
#pragma unroll
    for (int hh = 0; hh < H; ++hh) invd[hh] = 1.f / (d[hh] + 1e-16f);

    // pass 2: accumulate; lane owns channels [lane*4, lane*4+4)
    f32x2 acc01 = {0.f, 0.f}, acc23 = {0.f, 0.f};
    const int head = (H == 4) ? (lane >> 4) : 0;
    const u8* hb = h;
    const u32 laneB = (u32)lane * 4u;
    for (int base = start; base < end; base += 64) {
        int cnt = min(64, end - base);
        if (lane < cnt) {
            int s = csr_src[base + lane];
            u32 off = (u32)s * (u32)HIDC;           // fp8: 1 B per channel
            if (H == 4) {
                float4 a4 = *(const float4*)(asrc + s * 4);
                uint4 w0, w1;
                w0.x = off;
                w0.y = __float_as_uint(__expf(lk(a4.x + ad[0]) - m[0]) * invd[0]);
                w0.z = off;
                w0.w = __float_as_uint(__expf(lk(a4.y + ad[1 % H]) - m[1 % H]) * invd[1 % H]);
                w1.x = off;
                w1.y = __float_as_uint(__expf(lk(a4.z + ad[2 % H]) - m[2 % H]) * invd[2 % H]);
                w1.z = off;
                w1.w = __float_as_uint(__expf(lk(a4.w + ad[3 % H]) - m[3 % H]) * invd[3 % H]);
                *(uint4*)&s_ed[wid][lane * 4] = w0;
                *(uint4*)&s_ed[wid][lane * 4 + 2] = w1;
            } else {
                float al = __expf(lk(asrc[s] + ad[0]) - m[0]) * invd[0];
                s_ed[wid][lane] = make_uint2(off, __float_as_uint(al));
            }
        }
        // wave-synchronous LDS: DS ops from one wave complete in order
#define GBODY(J) {                                                             \
            uint2 e_ = s_ed[wid][(H == 4) ? ((J) * 4 + head) : (J)];           \
            u32 hv_ = *(const u32*)(hb + (size_t)(e_.x + laneB));              \
            float al_ = __uint_as_float(e_.y);                                 \
            f32x2 al2_ = {al_, al_};                                           \
            f32x2 v01_ = __builtin_amdgcn_cvt_pk_f32_fp8(hv_, false);          \
            f32x2 v23_ = __builtin_amdgcn_cvt_pk_f32_fp8(hv_, true);           \
            acc01 = __builtin_elementwise_fma(v01_, al2_, acc01);              \
            acc23 = __builtin_elementwise_fma(v23_, al2_, acc23); }
        int j = 0;
        for (; j + 4 <= cnt; j += 4) { GBODY(j) GBODY(j + 1) GBODY(j + 2) GBODY(j + 3) }
        for (; j < cnt; ++j) GBODY(j)
#undef GBODY
    }
    uint2 o;
    o.x = pack2(acc01.x, acc01.y);
    o.y = pack2(acc23.x, acc23.y);
    ((uint2*)(agg + (size_t)n * HIDC))[lane] = o;
}

// ---------- BatchNorm stats (bf16 in, fp32 accumulate) ----------
__global__ __launch_bounds__(256)
void bn_stats_kernel(const u16* __restrict__ h, int N,
                     float* __restrict__ sum, float* __restrict__ sumsq) {
    int c = threadIdx.x;
    int r0 = blockIdx.x * 128;
    int rend = min(r0 + 128, N);
    float s = 0.f, q = 0.f;
    for (int r = r0; r < rend; ++r) {
        float v = b2f(h[(long)r * HIDC + c]);
        s += v;
        q += v * v;
    }
    atomicAdd(&sum[c], s);
    atomicAdd(&sumsq[c], q);
}

// ---------- graph mean pooling with inline BN+relu (batch sorted) ---------
__global__ __launch_bounds__(256)
void pool_bn_kernel(const u16* __restrict__ h, const int* __restrict__ batch,
                    int N, const float* __restrict__ scale,
                    const float* __restrict__ bias,
                    float* __restrict__ gsum, float* __restrict__ gcnt) {
    int c = threadIdx.x;
    float sc = scale[c], bi = bias[c];
    int r0 = blockIdx.x * 128;
    int rend = min(r0 + 128, N);
    int curb = -1;
    float acc = 0.f;
    for (int r = r0; r < rend; ++r) {
        int b = batch[r];
        if (b != curb) {
            if (curb >= 0) atomicAdd(&gsum[curb * HIDC + c], acc);
            curb = b; acc = 0.f;
        }
        acc += fmaxf(fmaf(sc, b2f(h[(long)r * HIDC + c]), bi), 0.f);
    }
    if (curb >= 0) atomicAdd(&gsum[curb * HIDC + c], acc);
    if (c == 0) {
        int prev = -1; float cnt = 0.f;
        for (int r = r0; r < rend; ++r) {
            int b = batch[r];
            if (b != prev) {
                if (prev >= 0) atomicAdd(&gcnt[prev], cnt);
                prev = b; cnt = 0.f;
            }
            cnt += 1.f;
        }
        if (prev >= 0) atomicAdd(&gcnt[prev], cnt);
    }
}

// ---------- gmean + projection: gproj[b,c] = Σ_k gmean[b,k]*Wq1[256+k,c] --
__global__ __launch_bounds__(256)
void gmean_gproj_kernel(const float* __restrict__ gsum,
                        const float* __restrict__ gcnt,
                        const float* __restrict__ Wq1,
                        float* __restrict__ gproj) {
    int b = blockIdx.x, c = threadIdx.x;
    __shared__ float gm[HIDC];
    gm[c] = gsum[b * HIDC + c] / fmaxf(gcnt[b], 1.f);
    __syncthreads();
    float acc = 0.f;
    for (int k = 0; k < HIDC; ++k)
        acc = fmaf(gm[k], Wq1[(long)(HIDC + k) * HIDC + c], acc);
    gproj[b * HIDC + c] = acc;
}

extern "C" void kernel_launch(void* const* d_in, const int* in_sizes, int n_in,
                              void* d_out, int out_size, void* d_ws, size_t ws_size,
                              hipStream_t stream) {
    const float* x   = (const float*)d_in[0];
    const int*   ei  = (const int*)d_in[1];
    const int*   bat = (const int*)d_in[2];
    const float* W1  = (const float*)d_in[3];
    const float* as1 = (const float*)d_in[4];
    const float* ad1 = (const float*)d_in[5];
    const float* g1  = (const float*)d_in[7];
    const float* be1 = (const float*)d_in[8];
    const float* W2  = (const float*)d_in[9];
    const float* as2 = (const float*)d_in[10];
    const float* ad2 = (const float*)d_in[11];
    const float* g2  = (const float*)d_in[13];
    const float* be2 = (const float*)d_in[14];
    const float* Wq1 = (const float*)d_in[15];
    const float* bq1 = (const float*)d_in[16];
    const float* Wq2 = (const float*)d_in[17];
    const float* bq2 = (const float*)d_in[18];
    float* out = (float*)d_out;

    const int N = in_sizes[0] / F_IN;   // 50000
    const int E = in_sizes[1] / 2;      // 800000
    const int Etot = E + N;
    const int nb = (N + 255) / 256;

    const size_t hbytes = (size_t)N * HIDC * sizeof(u16);   // 25.6 MB (bf16)
    char* p = (char*)d_ws;
    auto alloc = [&](size_t sz) { char* q = p; p += (sz + 255) & ~(size_t)255; return q; };
    u16* BX   = (u16*)alloc((size_t)N * F_IN * sizeof(u16)); // bf16 x
    u8*  BH   = (u8*)alloc((size_t)N * HIDC);  // h1 -> h2 (fp8, 12.8 MB)
    u16* BA   = (u16*)alloc(hbytes);   // agg1 -> agg2 (bf16)
    u16* WT1  = (u16*)alloc((size_t)HIDC * F_IN * sizeof(u16));
    u16* WT2  = (u16*)alloc((size_t)HIDC * HIDC * sizeof(u16));
    u16* WQT  = (u16*)alloc((size_t)HIDC * HIDC * sizeof(u16));
    // pairs sharing one memset are single allocations (alloc rounds to 256B!)
    float* asrc = (float*)alloc((size_t)N * 4 * 4 * 2);      // asrc | adst
    float* adst = asrc + (size_t)N * 4;
    int* rowptr  = (int*)alloc((size_t)(N + 1) * 4);
    int* csr_src = (int*)alloc((size_t)Etot * 4);
    int* cur     = (int*)alloc((size_t)N * 4 * 2);           // deg | fill cursor
    int* cur2    = cur + N;
    int* part    = (int*)alloc((size_t)N * 4);
    int* bsum    = (int*)alloc((size_t)nb * 4);
    float* bnsum = (float*)alloc(HIDC * 4 * 2);              // bnsum | bnsq
    float* bnsq  = bnsum + HIDC;
    float* sc1   = (float*)alloc(HIDC * 4);
    float* bi1   = (float*)alloc(HIDC * 4);
    float* sc2   = (float*)alloc(HIDC * 4);
    float* bi2   = (float*)alloc(HIDC * 4);
    float* gsum  = (float*)alloc((NG * HIDC + NG) * 4);      // gsum | gcnt
    float* gcnt  = gsum + NG * HIDC;
    float* gproj = (float*)alloc(NG * HIDC * 4);

    dim3 gemmGrid(2, (N + 127) / 128);   // block = 128 rows x 128 cols
    int edgeBlocks = (Etot + 255) / 256;
    int nodeBlocksW = (N + 3) / 4;
    int npair = N * F_IN / 2;
    int prepTotal = npair + F_IN * HIDC + 2 * HIDC * HIDC;

    // ===================== CSR build (once) ==============================
    hipMemsetAsync(cur, 0, (size_t)N * 4 * 2, stream);        // cur + cur2
    deg_kernel<<<edgeBlocks, 256, 0, stream>>>(ei, E, N, cur);
    scan_phase1<<<nb, 256, 0, stream>>>(cur, part, bsum, N);
    scan_phase2<<<1, 256, 0, stream>>>(bsum, nb);
    scan_phase3<<<nb, 256, 0, stream>>>(part, bsum, rowptr, N);
    fill_kernel<<<edgeBlocks, 256, 0, stream>>>(ei, E, N, rowptr, cur2, csr_src);

    // ===================== prep (1 dispatch) =============================
    prep_kernel<<<(prepTotal + 255) / 256, 256, 0, stream>>>(
        x, W1, W2, Wq1, (u32*)BX, WT1, WT2, WQT, npair);

    // ===================== Layer 1: GEMM(+alpha4) -> gather -> BN stats ==
    gemm_mfma_kernel<F_IN, 0><<<gemmGrid, 256, 0, stream>>>(
        BX, WT1, BH, N, nullptr, nullptr, as1, ad1, asrc, adst,
        nullptr, nullptr, nullptr, nullptr, nullptr);
    gat_gather_kernel<4><<<nodeBlocksW, 256, 0, stream>>>(rowptr, csr_src, asrc, adst, BH, BA, N);
    hipMemsetAsync(bnsum, 0, HIDC * 4 * 2, stream);           // bnsum + bnsq
    bn_stats_kernel<<<(N + 127) / 128, 256, 0, stream>>>(BA, N, bnsum, bnsq);
    bn_coef_kernel<<<1, HIDC, 0, stream>>>(bnsum, bnsq, g1, be1, sc1, bi1, N);

    // ===================== Layer 2: GEMM(BN-A, +alpha1) -> gather -> BN ==
    hipMemsetAsync(asrc, 0, (size_t)N * 4 * 4 * 2, stream);   // asrc + adst
    gemm_mfma_kernel<HIDC, 1><<<gemmGrid, 256, 0, stream>>>(
        BA, WT2, BH, N, sc1, bi1, as2, ad2, asrc, adst,
        nullptr, nullptr, nullptr, nullptr, nullptr);
    gat_gather_kernel<1><<<nodeBlocksW, 256, 0, stream>>>(rowptr, csr_src, asrc, adst, BH, BA, N);
    hipMemsetAsync(bnsum, 0, HIDC * 4 * 2, stream);
    bn_stats_kernel<<<(N + 127) / 128, 256, 0, stream>>>(BA, N, bnsum, bnsq);
    bn_coef_kernel<<<1, HIDC, 0, stream>>>(bnsum, bnsq, g2, be2, sc2, bi2, N);

    // ===================== Pool (BN inline) + projection + out init ======
    hipMemsetAsync(gsum, 0, (NG * HIDC + NG) * 4, stream);    // gsum + gcnt
    pool_bn_kernel<<<(N + 127) / 128, 256, 0, stream>>>(BA, bat, N, sc2, bi2, gsum, gcnt);
    gmean_gproj_kernel<<<NG, HIDC, 0, stream>>>(gsum, gcnt, Wq1, gproj);
    out_init_kernel<<<(N * 5 + 255) / 256, 256, 0, stream>>>(out, bq2, bat, N);

    // ===================== Head: GEMM(BN-A, fused q epilogue) ============
    gemm_mfma_kernel<HIDC, 2><<<gemmGrid, 256, 0, stream>>>(
        BA, WQT, nullptr, N, sc2, bi2, nullptr, nullptr, nullptr, nullptr,
        gproj, bat, bq1, Wq2, out);
}

// Round 9
// 530.459 us; speedup vs baseline: 1.0640x; 1.0287x over previous
//
#include <hip/hip_runtime.h>
#include <hip/hip_bf16.h>
#include <math.h>

#define F_IN  128
#define HIDC  256
#define NG    8
#define EPS_BN 1e-5f

typedef unsigned short u16;
typedef unsigned int   u32;
typedef unsigned char  u8;
typedef __attribute__((ext_vector_type(8))) short bf16x8;
typedef __attribute__((ext_vector_type(4))) float f32x4;
typedef __attribute__((ext_vector_type(2))) float f32x2;

// ---------- bf16 helpers ----------
static __device__ __forceinline__ float b2f(u16 u) {
    return __uint_as_float((u32)u << 16);
}
static __device__ __forceinline__ u16 f2b(float f) {   // RNE
    u32 u = __float_as_uint(f);
    u32 r = (u + 0x7fffu + ((u >> 16) & 1u)) >> 16;
    return (u16)r;
}
static __device__ __forceinline__ u32 pack2(float a, float b) {
    return (u32)f2b(a) | ((u32)f2b(b) << 16);
}
static __device__ __forceinline__ float lk(float v) {   // leaky relu 0.2
    return v >= 0.f ? v : 0.2f * v;
}
static __device__ __forceinline__ u8 f2fp8(float v) {  // e4m3 via HW cvt
    return (u8)__builtin_amdgcn_cvt_pk_fp8_f32(v, v, 0, false);
}

// ---------- prep: x->bf16 pairs + 3 weight transposes, one dispatch -------
__global__ void prep_kernel(const float* __restrict__ x,
                            const float* __restrict__ W1,
                            const float* __restrict__ W2,
                            const float* __restrict__ Wq1,
                            u32* __restrict__ xb, u16* __restrict__ WT1,
                            u16* __restrict__ WT2, u16* __restrict__ WQT,
                            int npair) {
    int i = blockIdx.x * 256 + threadIdx.x;
    if (i < npair) {
        float2 v = ((const float2*)x)[i];
        xb[i] = pack2(v.x, v.y);
        return;
    }
    i -= npair;
    if (i < F_IN * HIDC) {
        int nn = i / F_IN, k = i % F_IN;
        WT1[i] = f2b(W1[(long)k * HIDC + nn]);
        return;
    }
    i -= F_IN * HIDC;
    if (i < HIDC * HIDC) {
        int nn = i / HIDC, k = i % HIDC;
        WT2[i] = f2b(W2[(long)k * HIDC + nn]);
        return;
    }
    i -= HIDC * HIDC;
    if (i < HIDC * HIDC) {
        int nn = i / HIDC, k = i % HIDC;
        WQT[i] = f2b(Wq1[(long)k * HIDC + nn]);
    }
}

// ---------- out init: q part = bq2 broadcast, tail = batch as float -------
__global__ void out_init_kernel(float* __restrict__ out,
                                const float* __restrict__ bq2,
                                const int* __restrict__ batch, int N) {
    int i = blockIdx.x * 256 + threadIdx.x;
    if (i < N * 4) out[i] = bq2[i & 3];
    else if (i < N * 5) out[i] = (float)batch[i - N * 4];
}

// ---------- BN coefficients: scale = g*rsqrt(var), bias = beta - mu*scale --
__global__ void bn_coef_kernel(const float* __restrict__ sum,
                               const float* __restrict__ sumsq,
                               const float* __restrict__ gamma,
                               const float* __restrict__ beta,
                               float* __restrict__ scale,
                               float* __restrict__ bias, int N) {
    int c = threadIdx.x;
    float invN = 1.f / (float)N;
    float mu = sum[c] * invN;
    float var = sumsq[c] * invN - mu * mu;
    float inv = rsqrtf(var + EPS_BN);
    float sc = gamma[c] * inv;
    scale[c] = sc;
    bias[c] = beta[c] - mu * sc;
}

// ---------- MFMA GEMM: C = act(A)[M,K] @ WT^T, K-tiled LDS-staged B -------
// LDS tile = 128 cols x 128 K (34.8 KB -> 4 blocks/CU vs 66 KB -> 2).
// MODE 0: plain A, stores C (fp8 e4m3) + H=4 alpha logits (fp32).
// MODE 1: BN+relu A, stores C (fp8) + H=1 alpha logits (atomicAdd).
// MODE 2: BN+relu A, no C store; fused head: q += relu(acc+gproj+bq1).Wq2.
// Out-of-range waves stay alive (clamped reads, guarded stores) because the
// K-tile loop contains barriers.
template <int K, int MODE>
__global__ __launch_bounds__(256)
void gemm_mfma_kernel(const u16* __restrict__ A, const u16* __restrict__ WT,
                      u8* __restrict__ C, int M,
                      const float* __restrict__ scaleA, const float* __restrict__ biasA,
                      const float* __restrict__ wsrc, const float* __restrict__ wdst,
                      float* __restrict__ asrc, float* __restrict__ adst,
                      const float* __restrict__ gproj, const int* __restrict__ bat,
                      const float* __restrict__ bq1,
                      const float* __restrict__ wq2, float* __restrict__ qout) {
    constexpr int BK = 128;                    // K-tile width (K % 128 == 0)
    constexpr int ROWCH = BK / 8;              // uint4 chunks per row-tile
    __shared__ u16 sB[128][BK + 8];            // 34,816 B
    int tid = threadIdx.x;
    int n0 = blockIdx.x * 128;

    int wid = tid >> 6, lane = tid & 63;
    int row = lane & 15, quad = lane >> 4;
    int m0 = blockIdx.y * 128 + wid * 32;
    int mf0 = m0, mf1 = m0 + 16;               // M % 16 == 0
    bool v0 = mf0 < M, v1 = mf1 < M;
    int mr0 = v0 ? mf0 : 0, mr1 = v1 ? mf1 : 0;  // clamp: harmless reads
    const u16* Ap0 = A + (size_t)(mr0 + row) * K + quad * 8;
    const u16* Ap1 = A + (size_t)(mr1 + row) * K + quad * 8;

    f32x4 acc[2][8];
#pragma unroll
    for (int f = 0; f < 2; ++f)
#pragma unroll
        for (int t = 0; t < 8; ++t) acc[f][t] = (f32x4){0.f, 0.f, 0.f, 0.f};

#pragma unroll
    for (int kt = 0; kt < K; kt += BK) {
        if (kt > 0) __syncthreads();           // prior tile reads complete
        for (int i = tid; i < 128 * ROWCH; i += 256) {
            int r = i / ROWCH, c = i % ROWCH;
            *(uint4*)&sB[r][c * 8] =
                *(const uint4*)(WT + (size_t)(n0 + r) * K + kt + c * 8);
        }
        __syncthreads();
#pragma unroll
        for (int kk = 0; kk < BK; kk += 32) {
            int k0 = kt + kk;
            bf16x8 a[2];
            a[0] = *(const bf16x8*)(Ap0 + k0);
            a[1] = *(const bf16x8*)(Ap1 + k0);
            if constexpr (MODE != 0) {   // fused BN + relu on A fragments
                int c0 = k0 + quad * 8;
                float4 s0 = *(const float4*)(scaleA + c0);
                float4 s1 = *(const float4*)(scaleA + c0 + 4);
                float4 b0 = *(const float4*)(biasA + c0);
                float4 b1 = *(const float4*)(biasA + c0 + 4);
#pragma unroll
                for (int f = 0; f < 2; ++f) {
                    float xv[8];
#pragma unroll
                    for (int j = 0; j < 8; ++j) xv[j] = b2f((u16)a[f][j]);
                    xv[0] = fmaxf(fmaf(s0.x, xv[0], b0.x), 0.f);
                    xv[1] = fmaxf(fmaf(s0.y, xv[1], b0.y), 0.f);
                    xv[2] = fmaxf(fmaf(s0.z, xv[2], b0.z), 0.f);
                    xv[3] = fmaxf(fmaf(s0.w, xv[3], b0.w), 0.f);
                    xv[4] = fmaxf(fmaf(s1.x, xv[4], b1.x), 0.f);
                    xv[5] = fmaxf(fmaf(s1.y, xv[5], b1.y), 0.f);
                    xv[6] = fmaxf(fmaf(s1.z, xv[6], b1.z), 0.f);
                    xv[7] = fmaxf(fmaf(s1.w, xv[7], b1.w), 0.f);
#pragma unroll
                    for (int j = 0; j < 8; ++j) a[f][j] = (short)f2b(xv[j]);
                }
            }
#pragma unroll
            for (int t = 0; t < 8; ++t) {
                bf16x8 b = *(const bf16x8*)&sB[t * 16 + row][kk + quad * 8];
                acc[0][t] = __builtin_amdgcn_mfma_f32_16x16x32_bf16(a[0], b, acc[0][t], 0, 0, 0);
                acc[1][t] = __builtin_amdgcn_mfma_f32_16x16x32_bf16(a[1], b, acc[1][t], 0, 0, 0);
            }
        }
    }

    int mf[2] = {mf0, mf1};
    bool vf[2] = {v0, v1};
    if constexpr (MODE == 2) {       // fused head + q epilogue (no C store)
        float qacc[2][4][4];
#pragma unroll
        for (int f = 0; f < 2; ++f)
#pragma unroll
            for (int r = 0; r < 4; ++r)
#pragma unroll
                for (int j = 0; j < 4; ++j) qacc[f][r][j] = 0.f;
#pragma unroll
        for (int f = 0; f < 2; ++f) {
            if (!vf[f]) continue;
            int bm[4];
#pragma unroll
            for (int r = 0; r < 4; ++r) bm[r] = bat[mf[f] + quad * 4 + r];
#pragma unroll
            for (int t = 0; t < 8; ++t) {
                int n = n0 + t * 16 + row;
                float bq = bq1[n];
                float4 w4 = ((const float4*)wq2)[n];
#pragma unroll
                for (int r = 0; r < 4; ++r) {
                    float v = fmaxf(acc[f][t][r] + gproj[bm[r] * HIDC + n] + bq, 0.f);
                    qacc[f][r][0] = fmaf(v, w4.x, qacc[f][r][0]);
                    qacc[f][r][1] = fmaf(v, w4.y, qacc[f][r][1]);
                    qacc[f][r][2] = fmaf(v, w4.z, qacc[f][r][2]);
                    qacc[f][r][3] = fmaf(v, w4.w, qacc[f][r][3]);
                }
            }
        }
#pragma unroll
        for (int off = 1; off < 16; off <<= 1)
#pragma unroll
            for (int f = 0; f < 2; ++f)
#pragma unroll
                for (int r = 0; r < 4; ++r)
#pragma unroll
                    for (int j = 0; j < 4; ++j)
                        qacc[f][r][j] += __shfl_xor(qacc[f][r][j], off, 64);
        if (row == 0) {
#pragma unroll
            for (int f = 0; f < 2; ++f) {
                if (!vf[f]) continue;
#pragma unroll
                for (int r = 0; r < 4; ++r) {
                    size_t m = mf[f] + quad * 4 + r;
#pragma unroll
                    for (int j = 0; j < 4; ++j)
                        atomicAdd(&qout[m * 4 + j], qacc[f][r][j]);
                }
            }
        }
    } else {
#pragma unroll
        for (int f = 0; f < 2; ++f) {
            if (!vf[f]) continue;
#pragma unroll
            for (int t = 0; t < 8; ++t) {
                int n = n0 + t * 16 + row;
#pragma unroll
                for (int r = 0; r < 4; ++r)
                    C[(size_t)(mf[f] + quad * 4 + r) * HIDC + n] = f2fp8(acc[f][t][r]);
            }
        }
        if constexpr (MODE == 0) {   // H=4 alpha logits; block owns 2 heads
            float pa[2][2][4] = {}, pd[2][2][4] = {};
#pragma unroll
            for (int t = 0; t < 8; ++t) {
                float ws = wsrc[n0 + t * 16 + row];
                float wd = wdst[n0 + t * 16 + row];
                int hf = t >> 2;
#pragma unroll
                for (int f = 0; f < 2; ++f)
#pragma unroll
                    for (int r = 0; r < 4; ++r) {
                        pa[f][hf][r] = fmaf(acc[f][t][r], ws, pa[f][hf][r]);
                        pd[f][hf][r] = fmaf(acc[f][t][r], wd, pd[f][hf][r]);
                    }
            }
#pragma unroll
            for (int off = 1; off < 16; off <<= 1)
#pragma unroll
                for (int f = 0; f < 2; ++f)
#pragma unroll
                    for (int hf = 0; hf < 2; ++hf)
#pragma unroll
                        for (int r = 0; r < 4; ++r) {
                            pa[f][hf][r] += __shfl_xor(pa[f][hf][r], off, 64);
                            pd[f][hf][r] += __shfl_xor(pd[f][hf][r], off, 64);
                        }
            if (row == 0) {
                int hbase = n0 >> 6;
#pragma unroll
                for (int f = 0; f < 2; ++f) {
                    if (!vf[f]) continue;
#pragma unroll
                    for (int r = 0; r < 4; ++r) {
                        int m = mf[f] + quad * 4 + r;
#pragma unroll
                        for (int hf = 0; hf < 2; ++hf) {
                            asrc[m * 4 + hbase + hf] = pa[f][hf][r];
                            adst[m * 4 + hbase + hf] = pd[f][hf][r];
                        }
                    }
                }
            }
        }
        if constexpr (MODE == 1) {   // H=1 alpha logits; 2 blocks sum via atomics
            float pa[2][4] = {}, pd[2][4] = {};
#pragma unroll
            for (int t = 0; t < 8; ++t) {
                float ws = wsrc[n0 + t * 16 + row];
                float wd = wdst[n0 + t * 16 + row];
#pragma unroll
                for (int f = 0; f < 2; ++f)
#pragma unroll
                    for (int r = 0; r < 4; ++r) {
                        pa[f][r] = fmaf(acc[f][t][r], ws, pa[f][r]);
                        pd[f][r] = fmaf(acc[f][t][r], wd, pd[f][r]);
                    }
            }
#pragma unroll
            for (int off = 1; off < 16; off <<= 1)
#pragma unroll
                for (int f = 0; f < 2; ++f)
#pragma unroll
                    for (int r = 0; r < 4; ++r) {
                        pa[f][r] += __shfl_xor(pa[f][r], off, 64);
                        pd[f][r] += __shfl_xor(pd[f][r], off, 64);
                    }
            if (row == 0) {
#pragma unroll
                for (int f = 0; f < 2; ++f) {
                    if (!vf[f]) continue;
#pragma unroll
                    for (int r = 0; r < 4; ++r) {
                        int m = mf[f] + quad * 4 + r;
                        atomicAdd(&asrc[m], pa[f][r]);
                        atomicAdd(&adst[m], pd[f][r]);
                    }
                }
            }
        }
    }
}

// =================== CSR build (by destination), built once ===============
__global__ void deg_kernel(const int* __restrict__ ei, int E, int N,
                           int* __restrict__ deg) {
    int e = blockIdx.x * blockDim.x + threadIdx.x;
    if (e >= E + N) return;
    int d = (e < E) ? ei[E + e] : (e - E);
    atomicAdd(&deg[d], 1);
}

__global__ __launch_bounds__(256)
void scan_phase1(const int* __restrict__ deg, int* __restrict__ part,
                 int* __restrict__ bsum, int N) {
    __shared__ int tmp[256];
    int i = blockIdx.x * 256 + threadIdx.x;
    int v = (i < N) ? deg[i] : 0;
    tmp[threadIdx.x] = v;
    __syncthreads();
    for (int off = 1; off < 256; off <<= 1) {
        int t = (threadIdx.x >= off) ? tmp[threadIdx.x - off] : 0;
        __syncthreads();
        tmp[threadIdx.x] += t;
        __syncthreads();
    }
    if (i < N) part[i] = tmp[threadIdx.x];
    if (threadIdx.x == 255) bsum[blockIdx.x] = tmp[255];
}
__global__ __launch_bounds__(256)
void scan_phase2(int* __restrict__ bsum, int nb) {
    __shared__ int tmp[256];
    int v = (threadIdx.x < nb) ? bsum[threadIdx.x] : 0;
    tmp[threadIdx.x] = v;
    __syncthreads();
    for (int off = 1; off < 256; off <<= 1) {
        int t = (threadIdx.x >= off) ? tmp[threadIdx.x - off] : 0;
        __syncthreads();
        tmp[threadIdx.x] += t;
        __syncthreads();
    }
    if (threadIdx.x < nb)
        bsum[threadIdx.x] = threadIdx.x ? tmp[threadIdx.x - 1] : 0;
}
__global__ __launch_bounds__(256)
void scan_phase3(const int* __restrict__ part, const int* __restrict__ bsum,
                 int* __restrict__ rowptr, int N) {
    int i = blockIdx.x * 256 + threadIdx.x;
    if (i < N) rowptr[i + 1] = part[i] + bsum[blockIdx.x];
    if (i == 0) rowptr[0] = 0;
}

__global__ void fill_kernel(const int* __restrict__ ei, int E, int N,
                            const int* __restrict__ rowptr,
                            int* __restrict__ cur, int* __restrict__ csr_src) {
    int e = blockIdx.x * blockDim.x + threadIdx.x;
    if (e >= E + N) return;
    int s = (e < E) ? ei[e] : (e - E);
    int d = (e < E) ? ei[E + e] : (e - E);
    int pos = rowptr[d] + atomicAdd(&cur[d], 1);
    csr_src[pos] = s;
}

// ========== fused GAT edge-softmax + aggregation (online softmax) =========
// wave per dst node. h rows are fp8 e4m3 (256 B/row): per edge, 1 ds_read_b64
// (offset, alpha), 1 global dword (4 ch), 2 HW fp8->f32 cvt, 2 packed fma.
// Alpha logits (asrc/adst) remain fp32; agg output remains bf16.
template <int H>
__global__ __launch_bounds__(256)
void gat_gather_kernel(const int* __restrict__ rowptr,
                       const int* __restrict__ csr_src,
                       const float* __restrict__ asrc,
                       const float* __restrict__ adst,
                       const u8* __restrict__ h,
                       u16* __restrict__ agg, int N) {
    __shared__ __align__(16) uint2 s_ed[4][64 * H];
    int wid = threadIdx.x >> 6, lane = threadIdx.x & 63;
    int n = blockIdx.x * 4 + wid;
    if (n >= N) return;
    int start = rowptr[n], end = rowptr[n + 1];
    float ad[H];
#pragma unroll
    for (int hh = 0; hh < H; ++hh) ad[hh] = adst[n * H + hh];

    // pass 1: online softmax stats (m, d) per head
    float m[H], d[H];
#pragma unroll
    for (int hh = 0; hh < H; ++hh) { m[hh] = -1e30f; d[hh] = 0.f; }
    for (int i = start + lane; i < end; i += 64) {
        int s = csr_src[i];
        float av[H];
        if (H == 4) {
            float4 a4 = *(const float4*)(asrc + s * 4);
            av[0] = a4.x; av[1 % H] = a4.y; av[2 % H] = a4.z; av[3 % H] = a4.w;
        } else {
            av[0] = asrc[s];
        }
#pragma unroll
        for (int hh = 0; hh < H; ++hh) {
            float v = lk(av[hh] + ad[hh]);
            float mn = fmaxf(m[hh], v);
            d[hh] = fmaf(d[hh], __expf(m[hh] - mn), __expf(v - mn));
            m[hh] = mn;
        }
    }
#pragma unroll
    for (int off = 1; off < 64; off <<= 1)
#pragma unroll
        for (int hh = 0; hh < H; ++hh) {
            float mo = __shfl_xor(m[hh], off, 64);
            float dd = __shfl_xor(d[hh], off, 64);
            float mn = fmaxf(m[hh], mo);
            d[hh] = d[hh] * __expf(m[hh] - mn) + dd * __expf(mo - mn);
            m[hh] = mn;
        }
    float invd[H];
#pragma unroll
    for (int hh = 0; hh < H; ++hh) invd[hh] = 1.f / (d[hh] + 1e-16f);

    // pass 2: accumulate; lane owns channels [lane*4, lane*4+4)
    f32x2 acc01 = {0.f, 0.f}, acc23 = {0.f, 0.f};
    const int head = (H == 4) ? (lane >> 4) : 0;
    const u8* hb = h;
    const u32 laneB = (u32)lane * 4u;
    for (int base = start; base < end; base += 64) {
        int cnt = min(64, end - base);
        if (lane < cnt) {
            int s = csr_src[base + lane];
            u32 off = (u32)s * (u32)HIDC;           // fp8: 1 B per channel
            if (H == 4) {
                float4 a4 = *(const float4*)(asrc + s * 4);
                uint4 w0, w1;
                w0.x = off;
                w0.y = __float_as_uint(__expf(lk(a4.x + ad[0]) - m[0]) * invd[0]);
                w0.z = off;
                w0.w = __float_as_uint(__expf(lk(a4.y + ad[1 % H]) - m[1 % H]) * invd[1 % H]);
                w1.x = off;
                w1.y = __float_as_uint(__expf(lk(a4.z + ad[2 % H]) - m[2 % H]) * invd[2 % H]);
                w1.z = off;
                w1.w = __float_as_uint(__expf(lk(a4.w + ad[3 % H]) - m[3 % H]) * invd[3 % H]);
                *(uint4*)&s_ed[wid][lane * 4] = w0;
                *(uint4*)&s_ed[wid][lane * 4 + 2] = w1;
            } else {
                float al = __expf(lk(asrc[s] + ad[0]) - m[0]) * invd[0];
                s_ed[wid][lane] = make_uint2(off, __float_as_uint(al));
            }
        }
        // wave-synchronous LDS: DS ops from one wave complete in order
#define GBODY(J) {                                                             \
            uint2 e_ = s_ed[wid][(H == 4) ? ((J) * 4 + head) : (J)];           \
            u32 hv_ = *(const u32*)(hb + (size_t)(e_.x + laneB));              \
            float al_ = __uint_as_float(e_.y);                                 \
            f32x2 al2_ = {al_, al_};                                           \
            f32x2 v01_ = __builtin_amdgcn_cvt_pk_f32_fp8(hv_, false);          \
            f32x2 v23_ = __builtin_amdgcn_cvt_pk_f32_fp8(hv_, true);           \
            acc01 = __builtin_elementwise_fma(v01_, al2_, acc01);              \
            acc23 = __builtin_elementwise_fma(v23_, al2_, acc23); }
        int j = 0;
        for (; j + 4 <= cnt; j += 4) { GBODY(j) GBODY(j + 1) GBODY(j + 2) GBODY(j + 3) }
        for (; j < cnt; ++j) GBODY(j)
#undef GBODY
    }
    uint2 o;
    o.x = pack2(acc01.x, acc01.y);
    o.y = pack2(acc23.x, acc23.y);
    ((uint2*)(agg + (size_t)n * HIDC))[lane] = o;
}

// ---------- BatchNorm stats (bf16 in, fp32 accumulate) ----------
__global__ __launch_bounds__(256)
void bn_stats_kernel(const u16* __restrict__ h, int N,
                     float* __restrict__ sum, float* __restrict__ sumsq) {
    int c = threadIdx.x;
    int r0 = blockIdx.x * 128;
    int rend = min(r0 + 128, N);
    float s = 0.f, q = 0.f;
    for (int r = r0; r < rend; ++r) {
        float v = b2f(h[(long)r * HIDC + c]);
        s += v;
        q += v * v;
    }
    atomicAdd(&sum[c], s);
    atomicAdd(&sumsq[c], q);
}

// ---------- graph mean pooling with inline BN+relu (batch sorted) ---------
__global__ __launch_bounds__(256)
void pool_bn_kernel(const u16* __restrict__ h, const int* __restrict__ batch,
                    int N, const float* __restrict__ scale,
                    const float* __restrict__ bias,
                    float* __restrict__ gsum, float* __restrict__ gcnt) {
    int c = threadIdx.x;
    float sc = scale[c], bi = bias[c];
    int r0 = blockIdx.x * 128;
    int rend = min(r0 + 128, N);
    int curb = -1;
    float acc = 0.f;
    for (int r = r0; r < rend; ++r) {
        int b = batch[r];
        if (b != curb) {
            if (curb >= 0) atomicAdd(&gsum[curb * HIDC + c], acc);
            curb = b; acc = 0.f;
        }
        acc += fmaxf(fmaf(sc, b2f(h[(long)r * HIDC + c]), bi), 0.f);
    }
    if (curb >= 0) atomicAdd(&gsum[curb * HIDC + c], acc);
    if (c == 0) {
        int prev = -1; float cnt = 0.f;
        for (int r = r0; r < rend; ++r) {
            int b = batch[r];
            if (b != prev) {
                if (prev >= 0) atomicAdd(&gcnt[prev], cnt);
                prev = b; cnt = 0.f;
            }
            cnt += 1.f;
        }
        if (prev >= 0) atomicAdd(&gcnt[prev], cnt);
    }
}

// ---------- gmean + projection: gproj[b,c] = Σ_k gmean[b,k]*Wq1[256+k,c] --
__global__ __launch_bounds__(256)
void gmean_gproj_kernel(const float* __restrict__ gsum,
                        const float* __restrict__ gcnt,
                        const float* __restrict__ Wq1,
                        float* __restrict__ gproj) {
    int b = blockIdx.x, c = threadIdx.x;
    __shared__ float gm[HIDC];
    gm[c] = gsum[b * HIDC + c] / fmaxf(gcnt[b], 1.f);
    __syncthreads();
    float acc = 0.f;
    for (int k = 0; k < HIDC; ++k)
        acc = fmaf(gm[k], Wq1[(long)(HIDC + k) * HIDC + c], acc);
    gproj[b * HIDC + c] = acc;
}

extern "C" void kernel_launch(void* const* d_in, const int* in_sizes, int n_in,
                              void* d_out, int out_size, void* d_ws, size_t ws_size,
                              hipStream_t stream) {
    const float* x   = (const float*)d_in[0];
    const int*   ei  = (const int*)d_in[1];
    const int*   bat = (const int*)d_in[2];
    const float* W1  = (const float*)d_in[3];
    const float* as1 = (const float*)d_in[4];
    const float* ad1 = (const float*)d_in[5];
    const float* g1  = (const float*)d_in[7];
    const float* be1 = (const float*)d_in[8];
    const float* W2  = (const float*)d_in[9];
    const float* as2 = (const float*)d_in[10];
    const float* ad2 = (const float*)d_in[11];
    const float* g2  = (const float*)d_in[13];
    const float* be2 = (const float*)d_in[14];
    const float* Wq1 = (const float*)d_in[15];
    const float* bq1 = (const float*)d_in[16];
    const float* Wq2 = (const float*)d_in[17];
    const float* bq2 = (const float*)d_in[18];
    float* out = (float*)d_out;

    const int N = in_sizes[0] / F_IN;   // 50000
    const int E = in_sizes[1] / 2;      // 800000
    const int Etot = E + N;
    const int nb = (N + 255) / 256;

    const size_t hbytes = (size_t)N * HIDC * sizeof(u16);   // 25.6 MB (bf16)
    char* p = (char*)d_ws;
    auto alloc = [&](size_t sz) { char* q = p; p += (sz + 255) & ~(size_t)255; return q; };
    u16* BX   = (u16*)alloc((size_t)N * F_IN * sizeof(u16)); // bf16 x
    u8*  BH   = (u8*)alloc((size_t)N * HIDC);  // h1 -> h2 (fp8, 12.8 MB)
    u16* BA   = (u16*)alloc(hbytes);   // agg1 -> agg2 (bf16)
    u16* WT1  = (u16*)alloc((size_t)HIDC * F_IN * sizeof(u16));
    u16* WT2  = (u16*)alloc((size_t)HIDC * HIDC * sizeof(u16));
    u16* WQT  = (u16*)alloc((size_t)HIDC * HIDC * sizeof(u16));
    // pairs sharing one memset are single allocations (alloc rounds to 256B!)
    float* asrc = (float*)alloc((size_t)N * 4 * 4 * 2);      // asrc | adst
    float* adst = asrc + (size_t)N * 4;
    int* rowptr  = (int*)alloc((size_t)(N + 1) * 4);
    int* csr_src = (int*)alloc((size_t)Etot * 4);
    int* cur     = (int*)alloc((size_t)N * 4 * 2);           // deg | fill cursor
    int* cur2    = cur + N;
    int* part    = (int*)alloc((size_t)N * 4);
    int* bsum    = (int*)alloc((size_t)nb * 4);
    float* bnsum = (float*)alloc(HIDC * 4 * 2);              // bnsum | bnsq
    float* bnsq  = bnsum + HIDC;
    float* sc1   = (float*)alloc(HIDC * 4);
    float* bi1   = (float*)alloc(HIDC * 4);
    float* sc2   = (float*)alloc(HIDC * 4);
    float* bi2   = (float*)alloc(HIDC * 4);
    float* gsum  = (float*)alloc((NG * HIDC + NG) * 4);      // gsum | gcnt
    float* gcnt  = gsum + NG * HIDC;
    float* gproj = (float*)alloc(NG * HIDC * 4);

    dim3 gemmGrid(2, (N + 127) / 128);   // block = 128 rows x 128 cols
    int edgeBlocks = (Etot + 255) / 256;
    int nodeBlocksW = (N + 3) / 4;
    int npair = N * F_IN / 2;
    int prepTotal = npair + F_IN * HIDC + 2 * HIDC * HIDC;

    // ===================== CSR build (once) ==============================
    hipMemsetAsync(cur, 0, (size_t)N * 4 * 2, stream);        // cur + cur2
    deg_kernel<<<edgeBlocks, 256, 0, stream>>>(ei, E, N, cur);
    scan_phase1<<<nb, 256, 0, stream>>>(cur, part, bsum, N);
    scan_phase2<<<1, 256, 0, stream>>>(bsum, nb);
    scan_phase3<<<nb, 256, 0, stream>>>(part, bsum, rowptr, N);
    fill_kernel<<<edgeBlocks, 256, 0, stream>>>(ei, E, N, rowptr, cur2, csr_src);

    // ===================== prep (1 dispatch) =============================
    prep_kernel<<<(prepTotal + 255) / 256, 256, 0, stream>>>(
        x, W1, W2, Wq1, (u32*)BX, WT1, WT2, WQT, npair);

    // ===================== Layer 1: GEMM(+alpha4) -> gather -> BN stats ==
    gemm_mfma_kernel<F_IN, 0><<<gemmGrid, 256, 0, stream>>>(
        BX, WT1, BH, N, nullptr, nullptr, as1, ad1, asrc, adst,
        nullptr, nullptr, nullptr, nullptr, nullptr);
    gat_gather_kernel<4><<<nodeBlocksW, 256, 0, stream>>>(rowptr, csr_src, asrc, adst, BH, BA, N);
    hipMemsetAsync(bnsum, 0, HIDC * 4 * 2, stream);           // bnsum + bnsq
    bn_stats_kernel<<<(N + 127) / 128, 256, 0, stream>>>(BA, N, bnsum, bnsq);
    bn_coef_kernel<<<1, HIDC, 0, stream>>>(bnsum, bnsq, g1, be1, sc1, bi1, N);

    // ===================== Layer 2: GEMM(BN-A, +alpha1) -> gather -> BN ==
    hipMemsetAsync(asrc, 0, (size_t)N * 4 * 4 * 2, stream);   // asrc + adst
    gemm_mfma_kernel<HIDC, 1><<<gemmGrid, 256, 0, stream>>>(
        BA, WT2, BH, N, sc1, bi1, as2, ad2, asrc, adst,
        nullptr, nullptr, nullptr, nullptr, nullptr);
    gat_gather_kernel<1><<<nodeBlocksW, 256, 0, stream>>>(rowptr, csr_src, asrc, adst, BH, BA, N);
    hipMemsetAsync(bnsum, 0, HIDC * 4 * 2, stream);
    bn_stats_kernel<<<(N + 127) / 128, 256, 0, stream>>>(BA, N, bnsum, bnsq);
    bn_coef_kernel<<<1, HIDC, 0, stream>>>(bnsum, bnsq, g2, be2, sc2, bi2, N);

    // ===================== Pool (BN inline) + projection + out init ======
    hipMemsetAsync(gsum, 0, (NG * HIDC + NG) * 4, stream);    // gsum + gcnt
    pool_bn_kernel<<<(N + 127) / 128, 256, 0, stream>>>(BA, bat, N, sc2, bi2, gsum, gcnt);
    gmean_gproj_kernel<<<NG, HIDC, 0, stream>>>(gsum, gcnt, Wq1, gproj);
    out_init_kernel<<<(N * 5 + 255) / 256, 256, 0, stream>>>(out, bq2, bat, N);

    // ===================== Head: GEMM(BN-A, fused q epilogue) ============
    gemm_mfma_kernel<HIDC, 2><<<gemmGrid, 256, 0, stream>>>(
        BA, WQT, nullptr, N, sc2, bi2, nullptr, nullptr, nullptr, nullptr,
        gproj, bat, bq1, Wq2, out);
}

// Round 10
// 511.750 us; speedup vs baseline: 1.1029x; 1.0366x over previous
//
#include <hip/hip_runtime.h>
#include <hip/hip_bf16.h>
#include <math.h>

#define F_IN  128
#define HIDC  256
#define NG    8
#define EPS_BN 1e-5f

typedef unsigned short u16;
typedef unsigned int   u32;
typedef unsigned char  u8;
typedef __attribute__((ext_vector_type(8))) short bf16x8;
typedef __attribute__((ext_vector_type(4))) float f32x4;
typedef __attribute__((ext_vector_type(2))) float f32x2;

// ---------- bf16 helpers ----------
static __device__ __forceinline__ float b2f(u16 u) {
    return __uint_as_float((u32)u << 16);
}
static __device__ __forceinline__ u16 f2b(float f) {   // RNE
    u32 u = __float_as_uint(f);
    u32 r = (u + 0x7fffu + ((u >> 16) & 1u)) >> 16;
    return (u16)r;
}
static __device__ __forceinline__ u32 pack2(float a, float b) {
    return (u32)f2b(a) | ((u32)f2b(b) << 16);
}
static __device__ __forceinline__ float lk(float v) {   // leaky relu 0.2
    return v >= 0.f ? v : 0.2f * v;
}
static __device__ __forceinline__ u8 f2fp8(float v) {  // e4m3 via HW cvt
    return (u8)__builtin_amdgcn_cvt_pk_fp8_f32(v, v, 0, false);
}

// ---------- prep: x->bf16 pairs + 3 weight transposes, one dispatch -------
__global__ void prep_kernel(const float* __restrict__ x,
                            const float* __restrict__ W1,
                            const float* __restrict__ W2,
                            const float* __restrict__ Wq1,
                            u32* __restrict__ xb, u16* __restrict__ WT1,
                            u16* __restrict__ WT2, u16* __restrict__ WQT,
                            int npair) {
    int i = blockIdx.x * 256 + threadIdx.x;
    if (i < npair) {
        float2 v = ((const float2*)x)[i];
        xb[i] = pack2(v.x, v.y);
        return;
    }
    i -= npair;
    if (i < F_IN * HIDC) {
        int nn = i / F_IN, k = i % F_IN;
        WT1[i] = f2b(W1[(long)k * HIDC + nn]);
        return;
    }
    i -= F_IN * HIDC;
    if (i < HIDC * HIDC) {
        int nn = i / HIDC, k = i % HIDC;
        WT2[i] = f2b(W2[(long)k * HIDC + nn]);
        return;
    }
    i -= HIDC * HIDC;
    if (i < HIDC * HIDC) {
        int nn = i / HIDC, k = i % HIDC;
        WQT[i] = f2b(Wq1[(long)k * HIDC + nn]);
    }
}

// ---------- out init: q part = bq2 broadcast, tail = batch as float -------
__global__ void out_init_kernel(float* __restrict__ out,
                                const float* __restrict__ bq2,
                                const int* __restrict__ batch, int N) {
    int i = blockIdx.x * 256 + threadIdx.x;
    if (i < N * 4) out[i] = bq2[i & 3];
    else if (i < N * 5) out[i] = (float)batch[i - N * 4];
}

// ---------- BN coefficients: scale = g*rsqrt(var), bias = beta - mu*scale --
__global__ void bn_coef_kernel(const float* __restrict__ sum,
                               const float* __restrict__ sumsq,
                               const float* __restrict__ gamma,
                               const float* __restrict__ beta,
                               float* __restrict__ scale,
                               float* __restrict__ bias, int N) {
    int c = threadIdx.x;
    float invN = 1.f / (float)N;
    float mu = sum[c] * invN;
    float var = sumsq[c] * invN - mu * mu;
    float inv = rsqrtf(var + EPS_BN);
    float sc = gamma[c] * inv;
    scale[c] = sc;
    bias[c] = beta[c] - mu * sc;
}

// ---------- MFMA GEMM: C = act(A)[M,K] @ WT^T, K-tiled LDS-staged B -------
// LDS tile = 128 cols x 128 K (34.8 KB -> 4 blocks/CU).
// MODE 0: plain A, stores C (fp8 e4m3) + H=4 alpha logits (fp32).
// MODE 1: BN+relu A, stores C (fp8) + H=1 alpha logits (atomicAdd).
// MODE 2: BN+relu A, no C store; fused head: q += relu(acc+gproj+bq1).Wq2.
template <int K, int MODE>
__global__ __launch_bounds__(256)
void gemm_mfma_kernel(const u16* __restrict__ A, const u16* __restrict__ WT,
                      u8* __restrict__ C, int M,
                      const float* __restrict__ scaleA, const float* __restrict__ biasA,
                      const float* __restrict__ wsrc, const float* __restrict__ wdst,
                      float* __restrict__ asrc, float* __restrict__ adst,
                      const float* __restrict__ gproj, const int* __restrict__ bat,
                      const float* __restrict__ bq1,
                      const float* __restrict__ wq2, float* __restrict__ qout) {
    constexpr int BK = 128;                    // K-tile width (K % 128 == 0)
    constexpr int ROWCH = BK / 8;              // uint4 chunks per row-tile
    __shared__ u16 sB[128][BK + 8];            // 34,816 B
    int tid = threadIdx.x;
    int n0 = blockIdx.x * 128;

    int wid = tid >> 6, lane = tid & 63;
    int row = lane & 15, quad = lane >> 4;
    int m0 = blockIdx.y * 128 + wid * 32;
    int mf0 = m0, mf1 = m0 + 16;               // M % 16 == 0
    bool v0 = mf0 < M, v1 = mf1 < M;
    int mr0 = v0 ? mf0 : 0, mr1 = v1 ? mf1 : 0;  // clamp: harmless reads
    const u16* Ap0 = A + (size_t)(mr0 + row) * K + quad * 8;
    const u16* Ap1 = A + (size_t)(mr1 + row) * K + quad * 8;

    f32x4 acc[2][8];
#pragma unroll
    for (int f = 0; f < 2; ++f)
#pragma unroll
        for (int t = 0; t < 8; ++t) acc[f][t] = (f32x4){0.f, 0.f, 0.f, 0.f};

#pragma unroll
    for (int kt = 0; kt < K; kt += BK) {
        if (kt > 0) __syncthreads();           // prior tile reads complete
        for (int i = tid; i < 128 * ROWCH; i += 256) {
            int r = i / ROWCH, c = i % ROWCH;
            *(uint4*)&sB[r][c * 8] =
                *(const uint4*)(WT + (size_t)(n0 + r) * K + kt + c * 8);
        }
        __syncthreads();
#pragma unroll
        for (int kk = 0; kk < BK; kk += 32) {
            int k0 = kt + kk;
            bf16x8 a[2];
            a[0] = *(const bf16x8*)(Ap0 + k0);
            a[1] = *(const bf16x8*)(Ap1 + k0);
            if constexpr (MODE != 0) {   // fused BN + relu on A fragments
                int c0 = k0 + quad * 8;
                float4 s0 = *(const float4*)(scaleA + c0);
                float4 s1 = *(const float4*)(scaleA + c0 + 4);
                float4 b0 = *(const float4*)(biasA + c0);
                float4 b1 = *(const float4*)(biasA + c0 + 4);
#pragma unroll
                for (int f = 0; f < 2; ++f) {
                    float xv[8];
#pragma unroll
                    for (int j = 0; j < 8; ++j) xv[j] = b2f((u16)a[f][j]);
                    xv[0] = fmaxf(fmaf(s0.x, xv[0], b0.x), 0.f);
                    xv[1] = fmaxf(fmaf(s0.y, xv[1], b0.y), 0.f);
                    xv[2] = fmaxf(fmaf(s0.z, xv[2], b0.z), 0.f);
                    xv[3] = fmaxf(fmaf(s0.w, xv[3], b0.w), 0.f);
                    xv[4] = fmaxf(fmaf(s1.x, xv[4], b1.x), 0.f);
                    xv[5] = fmaxf(fmaf(s1.y, xv[5], b1.y), 0.f);
                    xv[6] = fmaxf(fmaf(s1.z, xv[6], b1.z), 0.f);
                    xv[7] = fmaxf(fmaf(s1.w, xv[7], b1.w), 0.f);
#pragma unroll
                    for (int j = 0; j < 8; ++j) a[f][j] = (short)f2b(xv[j]);
                }
            }
#pragma unroll
            for (int t = 0; t < 8; ++t) {
                bf16x8 b = *(const bf16x8*)&sB[t * 16 + row][kk + quad * 8];
                acc[0][t] = __builtin_amdgcn_mfma_f32_16x16x32_bf16(a[0], b, acc[0][t], 0, 0, 0);
                acc[1][t] = __builtin_amdgcn_mfma_f32_16x16x32_bf16(a[1], b, acc[1][t], 0, 0, 0);
            }
        }
    }

    int mf[2] = {mf0, mf1};
    bool vf[2] = {v0, v1};
    if constexpr (MODE == 2) {       // fused head + q epilogue (no C store)
        float qacc[2][4][4];
#pragma unroll
        for (int f = 0; f < 2; ++f)
#pragma unroll
            for (int r = 0; r < 4; ++r)
#pragma unroll
                for (int j = 0; j < 4; ++j) qacc[f][r][j] = 0.f;
#pragma unroll
        for (int f = 0; f < 2; ++f) {
            if (!vf[f]) continue;
            int bm[4];
#pragma unroll
            for (int r = 0; r < 4; ++r) bm[r] = bat[mf[f] + quad * 4 + r];
#pragma unroll
            for (int t = 0; t < 8; ++t) {
                int n = n0 + t * 16 + row;
                float bq = bq1[n];
                float4 w4 = ((const float4*)wq2)[n];
#pragma unroll
                for (int r = 0; r < 4; ++r) {
                    float v = fmaxf(acc[f][t][r] + gproj[bm[r] * HIDC + n] + bq, 0.f);
                    qacc[f][r][0] = fmaf(v, w4.x, qacc[f][r][0]);
                    qacc[f][r][1] = fmaf(v, w4.y, qacc[f][r][1]);
                    qacc[f][r][2] = fmaf(v, w4.z, qacc[f][r][2]);
                    qacc[f][r][3] = fmaf(v, w4.w, qacc[f][r][3]);
                }
            }
        }
#pragma unroll
        for (int off = 1; off < 16; off <<= 1)
#pragma unroll
            for (int f = 0; f < 2; ++f)
#pragma unroll
                for (int r = 0; r < 4; ++r)
#pragma unroll
                    for (int j = 0; j < 4; ++j)
                        qacc[f][r][j] += __shfl_xor(qacc[f][r][j], off, 64);
        if (row == 0) {
#pragma unroll
            for (int f = 0; f < 2; ++f) {
                if (!vf[f]) continue;
#pragma unroll
                for (int r = 0; r < 4; ++r) {
                    size_t m = mf[f] + quad * 4 + r;
#pragma unroll
                    for (int j = 0; j < 4; ++j)
                        atomicAdd(&qout[m * 4 + j], qacc[f][r][j]);
                }
            }
        }
    } else {
#pragma unroll
        for (int f = 0; f < 2; ++f) {
            if (!vf[f]) continue;
#pragma unroll
            for (int t = 0; t < 8; ++t) {
                int n = n0 + t * 16 + row;
#pragma unroll
                for (int r = 0; r < 4; ++r)
                    C[(size_t)(mf[f] + quad * 4 + r) * HIDC + n] = f2fp8(acc[f][t][r]);
            }
        }
        if constexpr (MODE == 0) {   // H=4 alpha logits; block owns 2 heads
            float pa[2][2][4] = {}, pd[2][2][4] = {};
#pragma unroll
            for (int t = 0; t < 8; ++t) {
                float ws = wsrc[n0 + t * 16 + row];
                float wd = wdst[n0 + t * 16 + row];
                int hf = t >> 2;
#pragma unroll
                for (int f = 0; f < 2; ++f)
#pragma unroll
                    for (int r = 0; r < 4; ++r) {
                        pa[f][hf][r] = fmaf(acc[f][t][r], ws, pa[f][hf][r]);
                        pd[f][hf][r] = fmaf(acc[f][t][r], wd, pd[f][hf][r]);
                    }
            }
#pragma unroll
            for (int off = 1; off < 16; off <<= 1)
#pragma unroll
                for (int f = 0; f < 2; ++f)
#pragma unroll
                    for (int hf = 0; hf < 2; ++hf)
#pragma unroll
                        for (int r = 0; r < 4; ++r) {
                            pa[f][hf][r] += __shfl_xor(pa[f][hf][r], off, 64);
                            pd[f][hf][r] += __shfl_xor(pd[f][hf][r], off, 64);
                        }
            if (row == 0) {
                int hbase = n0 >> 6;
#pragma unroll
                for (int f = 0; f < 2; ++f) {
                    if (!vf[f]) continue;
#pragma unroll
                    for (int r = 0; r < 4; ++r) {
                        int m = mf[f] + quad * 4 + r;
#pragma unroll
                        for (int hf = 0; hf < 2; ++hf) {
                            asrc[m * 4 + hbase + hf] = pa[f][hf][r];
                            adst[m * 4 + hbase + hf] = pd[f][hf][r];
                        }
                    }
                }
            }
        }
        if constexpr (MODE == 1) {   // H=1 alpha logits; 2 blocks sum via atomics
            float pa[2][4] = {}, pd[2][4] = {};
#pragma unroll
            for (int t = 0; t < 8; ++t) {
                float ws = wsrc[n0 + t * 16 + row];
                float wd = wdst[n0 + t * 16 + row];
#pragma unroll
                for (int f = 0; f < 2; ++f)
#pragma unroll
                    for (int r = 0; r < 4; ++r) {
                        pa[f][r] = fmaf(acc[f][t][r], ws, pa[f][r]);
                        pd[f][r] = fmaf(acc[f][t][r], wd, pd[f][r]);
                    }
            }
#pragma unroll
            for (int off = 1; off < 16; off <<= 1)
#pragma unroll
                for (int f = 0; f < 2; ++f)
#pragma unroll
                    for (int r = 0; r < 4; ++r) {
                        pa[f][r] += __shfl_xor(pa[f][r], off, 64);
                        pd[f][r] += __shfl_xor(pd[f][r], off, 64);
                    }
            if (row == 0) {
#pragma unroll
                for (int f = 0; f < 2; ++f) {
                    if (!vf[f]) continue;
#pragma unroll
                    for (int r = 0; r < 4; ++r) {
                        int m = mf[f] + quad * 4 + r;
                        atomicAdd(&asrc[m], pa[f][r]);
                        atomicAdd(&adst[m], pd[f][r]);
                    }
                }
            }
        }
    }
}

// =================== CSR build (by destination), built once ===============
__global__ void deg_kernel(const int* __restrict__ ei, int E, int N,
                           int* __restrict__ deg) {
    int e = blockIdx.x * blockDim.x + threadIdx.x;
    if (e >= E + N) return;
    int d = (e < E) ? ei[E + e] : (e - E);
    atomicAdd(&deg[d], 1);
}

__global__ __launch_bounds__(256)
void scan_phase1(const int* __restrict__ deg, int* __restrict__ part,
                 int* __restrict__ bsum, int N) {
    __shared__ int tmp[256];
    int i = blockIdx.x * 256 + threadIdx.x;
    int v = (i < N) ? deg[i] : 0;
    tmp[threadIdx.x] = v;
    __syncthreads();
    for (int off = 1; off < 256; off <<= 1) {
        int t = (threadIdx.x >= off) ? tmp[threadIdx.x - off] : 0;
        __syncthreads();
        tmp[threadIdx.x] += t;
        __syncthreads();
    }
    if (i < N) part[i] = tmp[threadIdx.x];
    if (threadIdx.x == 255) bsum[blockIdx.x] = tmp[255];
}
__global__ __launch_bounds__(256)
void scan_phase2(int* __restrict__ bsum, int nb) {
    __shared__ int tmp[256];
    int v = (threadIdx.x < nb) ? bsum[threadIdx.x] : 0;
    tmp[threadIdx.x] = v;
    __syncthreads();
    for (int off = 1; off < 256; off <<= 1) {
        int t = (threadIdx.x >= off) ? tmp[threadIdx.x - off] : 0;
        __syncthreads();
        tmp[threadIdx.x] += t;
        __syncthreads();
    }
    if (threadIdx.x < nb)
        bsum[threadIdx.x] = threadIdx.x ? tmp[threadIdx.x - 1] : 0;
}
__global__ __launch_bounds__(256)
void scan_phase3(const int* __restrict__ part, const int* __restrict__ bsum,
                 int* __restrict__ rowptr, int N) {
    int i = blockIdx.x * 256 + threadIdx.x;
    if (i < N) rowptr[i + 1] = part[i] + bsum[blockIdx.x];
    if (i == 0) rowptr[0] = 0;
}

__global__ void fill_kernel(const int* __restrict__ ei, int E, int N,
                            const int* __restrict__ rowptr,
                            int* __restrict__ cur, int* __restrict__ csr_src) {
    int e = blockIdx.x * blockDim.x + threadIdx.x;
    if (e >= E + N) return;
    int s = (e < E) ? ei[e] : (e - E);
    int d = (e < E) ? ei[E + e] : (e - E);
    int pos = rowptr[d] + atomicAdd(&cur[d], 1);
    csr_src[pos] = s;
}

// ========== fused GAT edge-softmax + aggregation (deferred normalize) =====
// wave per dst node. Unnormalized accumulate acc = sum(exp(v-m) * h),
// wsum = sum(exp(v-m)); scale once at the end. Reductions are plain
// max-butterfly / sum-butterfly (no exp in the butterflies).
// Fast path deg<=64: one edge per lane, csr/asrc read exactly once.
template <int H>
__global__ __launch_bounds__(256)
void gat_gather_kernel(const int* __restrict__ rowptr,
                       const int* __restrict__ csr_src,
                       const float* __restrict__ asrc,
                       const float* __restrict__ adst,
                       const u8* __restrict__ h,
                       u16* __restrict__ agg, int N) {
    __shared__ __align__(16) uint2 s_ed[4][64 * H];
    int wid = threadIdx.x >> 6, lane = threadIdx.x & 63;
    int n = blockIdx.x * 4 + wid;
    if (n >= N) return;
    int start = rowptr[n], end = rowptr[n + 1];
    int deg = end - start;
    float ad[H];
#pragma unroll
    for (int hh = 0; hh < H; ++hh) ad[hh] = adst[n * H + hh];

    f32x2 acc01 = {0.f, 0.f}, acc23 = {0.f, 0.f};
    const int head = (H == 4) ? (lane >> 4) : 0;
    const u8* hb = h;
    const u32 laneB = (u32)lane * 4u;
    float wsum[H];

#define GBODY(J) {                                                             \
            uint2 e_ = s_ed[wid][(H == 4) ? ((J) * 4 + head) : (J)];           \
            u32 hv_ = *(const u32*)(hb + (size_t)(e_.x + laneB));              \
            float al_ = __uint_as_float(e_.y);                                 \
            f32x2 al2_ = {al_, al_};                                           \
            f32x2 v01_ = __builtin_amdgcn_cvt_pk_f32_fp8(hv_, false);          \
            f32x2 v23_ = __builtin_amdgcn_cvt_pk_f32_fp8(hv_, true);           \
            acc01 = __builtin_elementwise_fma(v01_, al2_, acc01);              \
            acc23 = __builtin_elementwise_fma(v23_, al2_, acc23); }

    if (deg <= 64) {
        // ---------- fast path: one edge per lane, single pass ----------
        float v[H];
#pragma unroll
        for (int hh = 0; hh < H; ++hh) v[hh] = -1e30f;
        u32 off = 0;
        if (lane < deg) {
            int s = csr_src[start + lane];
            off = (u32)s * (u32)HIDC;
            if (H == 4) {
                float4 a4 = *(const float4*)(asrc + s * 4);
                v[0] = lk(a4.x + ad[0]);
                v[1 % H] = lk(a4.y + ad[1 % H]);
                v[2 % H] = lk(a4.z + ad[2 % H]);
                v[3 % H] = lk(a4.w + ad[3 % H]);
            } else {
                v[0] = lk(asrc[s] + ad[0]);
            }
        }
        float m[H];
#pragma unroll
        for (int hh = 0; hh < H; ++hh) m[hh] = v[hh];
#pragma unroll
        for (int o = 1; o < 64; o <<= 1)
#pragma unroll
            for (int hh = 0; hh < H; ++hh)
                m[hh] = fmaxf(m[hh], __shfl_xor(m[hh], o, 64));
        float w[H];
#pragma unroll
        for (int hh = 0; hh < H; ++hh) {
            w[hh] = __expf(v[hh] - m[hh]);   // inactive lanes: exp(-huge) = 0
            wsum[hh] = w[hh];
        }
#pragma unroll
        for (int o = 1; o < 64; o <<= 1)
#pragma unroll
            for (int hh = 0; hh < H; ++hh)
                wsum[hh] += __shfl_xor(wsum[hh], o, 64);
        if (H == 4) {
            uint4 w0, w1;
            w0.x = off; w0.y = __float_as_uint(w[0]);
            w0.z = off; w0.w = __float_as_uint(w[1 % H]);
            w1.x = off; w1.y = __float_as_uint(w[2 % H]);
            w1.z = off; w1.w = __float_as_uint(w[3 % H]);
            *(uint4*)&s_ed[wid][lane * 4] = w0;
            *(uint4*)&s_ed[wid][lane * 4 + 2] = w1;
        } else {
            s_ed[wid][lane] = make_uint2(off, __float_as_uint(w[0]));
        }
        int j = 0;
        for (; j + 4 <= deg; j += 4) { GBODY(j) GBODY(j + 1) GBODY(j + 2) GBODY(j + 3) }
        for (; j < deg; ++j) GBODY(j)
    } else {
        // ---------- general path: max pass, then staged chunks ----------
        float m[H];
#pragma unroll
        for (int hh = 0; hh < H; ++hh) m[hh] = -1e30f;
        for (int i = start + lane; i < end; i += 64) {
            int s = csr_src[i];
            if (H == 4) {
                float4 a4 = *(const float4*)(asrc + s * 4);
                m[0] = fmaxf(m[0], lk(a4.x + ad[0]));
                m[1 % H] = fmaxf(m[1 % H], lk(a4.y + ad[1 % H]));
                m[2 % H] = fmaxf(m[2 % H], lk(a4.z + ad[2 % H]));
                m[3 % H] = fmaxf(m[3 % H], lk(a4.w + ad[3 % H]));
            } else {
                m[0] = fmaxf(m[0], lk(asrc[s] + ad[0]));
            }
        }
#pragma unroll
        for (int o = 1; o < 64; o <<= 1)
#pragma unroll
            for (int hh = 0; hh < H; ++hh)
                m[hh] = fmaxf(m[hh], __shfl_xor(m[hh], o, 64));
#pragma unroll
        for (int hh = 0; hh < H; ++hh) wsum[hh] = 0.f;
        for (int base = start; base < end; base += 64) {
            int cnt = min(64, end - base);
            if (lane < cnt) {
                int s = csr_src[base + lane];
                u32 off = (u32)s * (u32)HIDC;
                if (H == 4) {
                    float4 a4 = *(const float4*)(asrc + s * 4);
                    float w0f = __expf(lk(a4.x + ad[0]) - m[0]);
                    float w1f = __expf(lk(a4.y + ad[1 % H]) - m[1 % H]);
                    float w2f = __expf(lk(a4.z + ad[2 % H]) - m[2 % H]);
                    float w3f = __expf(lk(a4.w + ad[3 % H]) - m[3 % H]);
                    wsum[0] += w0f; wsum[1 % H] += w1f;
                    wsum[2 % H] += w2f; wsum[3 % H] += w3f;
                    uint4 w0, w1;
                    w0.x = off; w0.y = __float_as_uint(w0f);
                    w0.z = off; w0.w = __float_as_uint(w1f);
                    w1.x = off; w1.y = __float_as_uint(w2f);
                    w1.z = off; w1.w = __float_as_uint(w3f);
                    *(uint4*)&s_ed[wid][lane * 4] = w0;
                    *(uint4*)&s_ed[wid][lane * 4 + 2] = w1;
                } else {
                    float wf = __expf(lk(asrc[s] + ad[0]) - m[0]);
                    wsum[0] += wf;
                    s_ed[wid][lane] = make_uint2(off, __float_as_uint(wf));
                }
            }
            int j = 0;
            for (; j + 4 <= cnt; j += 4) { GBODY(j) GBODY(j + 1) GBODY(j + 2) GBODY(j + 3) }
            for (; j < cnt; ++j) GBODY(j)
        }
#pragma unroll
        for (int o = 1; o < 64; o <<= 1)
#pragma unroll
            for (int hh = 0; hh < H; ++hh)
                wsum[hh] += __shfl_xor(wsum[hh], o, 64);
    }
#undef GBODY
    float sc = 1.f / (wsum[head] + 1e-16f);
    f32x2 sc2 = {sc, sc};
    acc01 *= sc2;
    acc23 *= sc2;
    uint2 o;
    o.x = pack2(acc01.x, acc01.y);
    o.y = pack2(acc23.x, acc23.y);
    ((uint2*)(agg + (size_t)n * HIDC))[lane] = o;
}

// ---------- BatchNorm stats (bf16 in, fp32 accumulate) ----------
__global__ __launch_bounds__(256)
void bn_stats_kernel(const u16* __restrict__ h, int N,
                     float* __restrict__ sum, float* __restrict__ sumsq) {
    int c = threadIdx.x;
    int r0 = blockIdx.x * 128;
    int rend = min(r0 + 128, N);
    float s = 0.f, q = 0.f;
    for (int r = r0; r < rend; ++r) {
        float v = b2f(h[(long)r * HIDC + c]);
        s += v;
        q += v * v;
    }
    atomicAdd(&sum[c], s);
    atomicAdd(&sumsq[c], q);
}

// ---------- graph mean pooling with inline BN+relu (batch sorted) ---------
__global__ __launch_bounds__(256)
void pool_bn_kernel(const u16* __restrict__ h, const int* __restrict__ batch,
                    int N, const float* __restrict__ scale,
                    const float* __restrict__ bias,
                    float* __restrict__ gsum, float* __restrict__ gcnt) {
    int c = threadIdx.x;
    float sc = scale[c], bi = bias[c];
    int r0 = blockIdx.x * 128;
    int rend = min(r0 + 128, N);
    int curb = -1;
    float acc = 0.f;
    for (int r = r0; r < rend; ++r) {
        int b = batch[r];
        if (b != curb) {
            if (curb >= 0) atomicAdd(&gsum[curb * HIDC + c], acc);
            curb = b; acc = 0.f;
        }
        acc += fmaxf(fmaf(sc, b2f(h[(long)r * HIDC + c]), bi), 0.f);
    }
    if (curb >= 0) atomicAdd(&gsum[curb * HIDC + c], acc);
    if (c == 0) {
        int prev = -1; float cnt = 0.f;
        for (int r = r0; r < rend; ++r) {
            int b = batch[r];
            if (b != prev) {
                if (prev >= 0) atomicAdd(&gcnt[prev], cnt);
                prev = b; cnt = 0.f;
            }
            cnt += 1.f;
        }
        if (prev >= 0) atomicAdd(&gcnt[prev], cnt);
    }
}

// ---------- gmean + projection: gproj[b,c] = Σ_k gmean[b,k]*Wq1[256+k,c] --
__global__ __launch_bounds__(256)
void gmean_gproj_kernel(const float* __restrict__ gsum,
                        const float* __restrict__ gcnt,
                        const float* __restrict__ Wq1,
                        float* __restrict__ gproj) {
    int b = blockIdx.x, c = threadIdx.x;
    __shared__ float gm[HIDC];
    gm[c] = gsum[b * HIDC + c] / fmaxf(gcnt[b], 1.f);
    __syncthreads();
    float acc = 0.f;
    for (int k = 0; k < HIDC; ++k)
        acc = fmaf(gm[k], Wq1[(long)(HIDC + k) * HIDC + c], acc);
    gproj[b * HIDC + c] = acc;
}

extern "C" void kernel_launch(void* const* d_in, const int* in_sizes, int n_in,
                              void* d_out, int out_size, void* d_ws, size_t ws_size,
                              hipStream_t stream) {
    const float* x   = (const float*)d_in[0];
    const int*   ei  = (const int*)d_in[1];
    const int*   bat = (const int*)d_in[2];
    const float* W1  = (const float*)d_in[3];
    const float* as1 = (const float*)d_in[4];
    const float* ad1 = (const float*)d_in[5];
    const float* g1  = (const float*)d_in[7];
    const float* be1 = (const float*)d_in[8];
    const float* W2  = (const float*)d_in[9];
    const float* as2 = (const float*)d_in[10];
    const float* ad2 = (const float*)d_in[11];
    const float* g2  = (const float*)d_in[13];
    const float* be2 = (const float*)d_in[14];
    const float* Wq1 = (const float*)d_in[15];
    const float* bq1 = (const float*)d_in[16];
    const float* Wq2 = (const float*)d_in[17];
    const float* bq2 = (const float*)d_in[18];
    float* out = (float*)d_out;

    const int N = in_sizes[0] / F_IN;   // 50000
    const int E = in_sizes[1] / 2;      // 800000
    const int Etot = E + N;
    const int nb = (N + 255) / 256;

    const size_t hbytes = (size_t)N * HIDC * sizeof(u16);   // 25.6 MB (bf16)
    char* p = (char*)d_ws;
    auto alloc = [&](size_t sz) { char* q = p; p += (sz + 255) & ~(size_t)255; return q; };
    u16* BX   = (u16*)alloc((size_t)N * F_IN * sizeof(u16)); // bf16 x
    u8*  BH   = (u8*)alloc((size_t)N * HIDC);  // h1 -> h2 (fp8, 12.8 MB)
    u16* BA   = (u16*)alloc(hbytes);   // agg1 -> agg2 (bf16)
    u16* WT1  = (u16*)alloc((size_t)HIDC * F_IN * sizeof(u16));
    u16* WT2  = (u16*)alloc((size_t)HIDC * HIDC * sizeof(u16));
    u16* WQT  = (u16*)alloc((size_t)HIDC * HIDC * sizeof(u16));
    // pairs sharing one memset are single allocations (alloc rounds to 256B!)
    float* asrc = (float*)alloc((size_t)N * 4 * 4 * 2);      // asrc | adst
    float* adst = asrc + (size_t)N * 4;
    int* rowptr  = (int*)alloc((size_t)(N + 1) * 4);
    int* csr_src = (int*)alloc((size_t)Etot * 4);
    int* cur     = (int*)alloc((size_t)N * 4 * 2);           // deg | fill cursor
    int* cur2    = cur + N;
    int* part    = (int*)alloc((size_t)N * 4);
    int* bsum    = (int*)alloc((size_t)nb * 4);
    float* bnsum = (float*)alloc(HIDC * 4 * 2);              // bnsum | bnsq
    float* bnsq  = bnsum + HIDC;
    float* sc1   = (float*)alloc(HIDC * 4);
    float* bi1   = (float*)alloc(HIDC * 4);
    float* sc2   = (float*)alloc(HIDC * 4);
    float* bi2   = (float*)alloc(HIDC * 4);
    float* gsum  = (float*)alloc((NG * HIDC + NG) * 4);      // gsum | gcnt
    float* gcnt  = gsum + NG * HIDC;
    float* gproj = (float*)alloc(NG * HIDC * 4);

    dim3 gemmGrid(2, (N + 127) / 128);   // block = 128 rows x 128 cols
    int edgeBlocks = (Etot + 255) / 256;
    int nodeBlocksW = (N + 3) / 4;
    int npair = N * F_IN / 2;
    int prepTotal = npair + F_IN * HIDC + 2 * HIDC * HIDC;

    // ===================== CSR build (once) ==============================
    hipMemsetAsync(cur, 0, (size_t)N * 4 * 2, stream);        // cur + cur2
    deg_kernel<<<edgeBlocks, 256, 0, stream>>>(ei, E, N, cur);
    scan_phase1<<<nb, 256, 0, stream>>>(cur, part, bsum, N);
    scan_phase2<<<1, 256, 0, stream>>>(bsum, nb);
    scan_phase3<<<nb, 256, 0, stream>>>(part, bsum, rowptr, N);
    fill_kernel<<<edgeBlocks, 256, 0, stream>>>(ei, E, N, rowptr, cur2, csr_src);

    // ===================== prep (1 dispatch) =============================
    prep_kernel<<<(prepTotal + 255) / 256, 256, 0, stream>>>(
        x, W1, W2, Wq1, (u32*)BX, WT1, WT2, WQT, npair);

    // ===================== Layer 1: GEMM(+alpha4) -> gather -> BN stats ==
    gemm_mfma_kernel<F_IN, 0><<<gemmGrid, 256, 0, stream>>>(
        BX, WT1, BH, N, nullptr, nullptr, as1, ad1, asrc, adst,
        nullptr, nullptr, nullptr, nullptr, nullptr);
    gat_gather_kernel<4><<<nodeBlocksW, 256, 0, stream>>>(rowptr, csr_src, asrc, adst, BH, BA, N);
    hipMemsetAsync(bnsum, 0, HIDC * 4 * 2, stream);           // bnsum + bnsq
    bn_stats_kernel<<<(N + 127) / 128, 256, 0, stream>>>(BA, N, bnsum, bnsq);
    bn_coef_kernel<<<1, HIDC, 0, stream>>>(bnsum, bnsq, g1, be1, sc1, bi1, N);

    // ===================== Layer 2: GEMM(BN-A, +alpha1) -> gather -> BN ==
    hipMemsetAsync(asrc, 0, (size_t)N * 4 * 4 * 2, stream);   // asrc + adst
    gemm_mfma_kernel<HIDC, 1><<<gemmGrid, 256, 0, stream>>>(
        BA, WT2, BH, N, sc1, bi1, as2, ad2, asrc, adst,
        nullptr, nullptr, nullptr, nullptr, nullptr);
    gat_gather_kernel<1><<<nodeBlocksW, 256, 0, stream>>>(rowptr, csr_src, asrc, adst, BH, BA, N);
    hipMemsetAsync(bnsum, 0, HIDC * 4 * 2, stream);
    bn_stats_kernel<<<(N + 127) / 128, 256, 0, stream>>>(BA, N, bnsum, bnsq);
    bn_coef_kernel<<<1, HIDC, 0, stream>>>(bnsum, bnsq, g2, be2, sc2, bi2, N);

    // ===================== Pool (BN inline) + projection + out init ======
    hipMemsetAsync(gsum, 0, (NG * HIDC + NG) * 4, stream);    // gsum + gcnt
    pool_bn_kernel<<<(N + 127) / 128, 256, 0, stream>>>(BA, bat, N, sc2, bi2, gsum, gcnt);
    gmean_gproj_kernel<<<NG, HIDC, 0, stream>>>(gsum, gcnt, Wq1, gproj);
    out_init_kernel<<<(N * 5 + 255) / 256, 256, 0, stream>>>(out, bq2, bat, N);

    // ===================== Head: GEMM(BN-A, fused q epilogue) ============
    gemm_mfma_kernel<HIDC, 2><<<gemmGrid, 256, 0, stream>>>(
        BA, WQT, nullptr, N, sc2, bi2, nullptr, nullptr, nullptr, nullptr,
        gproj, bat, bq1, Wq2, out);
}